// Round 4
// baseline (271.454 us; speedup 1.0000x reference)
//
#include <hip/hip_runtime.h>
#include <math.h>

typedef __attribute__((ext_vector_type(4))) float f32x4;
typedef __attribute__((ext_vector_type(8))) short s16x8;
typedef __attribute__((ext_vector_type(4))) short s16x4;
typedef __attribute__((ext_vector_type(4))) unsigned int u32x4;

#define NB 4
#define CH 128
#define ICH 64
#define NSP 4096
#define KSPLIT 16
#define SEGK (NSP / KSPLIT)   // 256
#define LDK 72    // LDS row stride (bf16): 144 B, 16B-aligned, 2-way banks only
#define LDW 136   // k_proj W LDS stride

static __device__ __forceinline__ unsigned short f2bf(float f) {
  unsigned int u = __builtin_bit_cast(unsigned int, f);
  u += 0x7fffu + ((u >> 16) & 1u);   // RNE
  return (unsigned short)(u >> 16);
}

// ---------------- Kernel 1: one projection per block (MFMA) ------------------
// z=0: thetaT [B][N][IC] (pre-scaled by log2e); z=1: phiT [B][N][IC]; z=2: g [B][IC][N]
__global__ __launch_bounds__(256) void k_proj(
    const float* __restrict__ x,
    const float* __restrict__ gw, const float* __restrict__ gbias,
    const float* __restrict__ tw, const float* __restrict__ tbias,
    const float* __restrict__ pw, const float* __restrict__ pbias,
    unsigned short* __restrict__ thetaT, unsigned short* __restrict__ phiT,
    unsigned short* __restrict__ gout)
{
  __shared__ __align__(16) float sxf[CH * 65];
  __shared__ __align__(16) unsigned short sW[ICH * LDW];
  const int b = blockIdx.y, z = blockIdx.z;
  const int n0 = blockIdx.x * 64;
  const int t = threadIdx.x;
  const float* Wz = (z == 0) ? tw : (z == 1) ? pw : gw;
  const float* Bz = (z == 0) ? tbias : (z == 1) ? pbias : gbias;
  const float scl = (z == 0) ? 1.44269504f : 1.0f;   // fold log2(e) into theta
  const float* xb = x + (size_t)b * CH * NSP;
#pragma unroll
  for (int i = 0; i < 8; ++i) {
    int idx = t + 256 * i;
    int c = idx >> 4, ch = idx & 15;
    *(float4*)(sxf + c * 65 + ch * 4) = *(const float4*)(xb + (size_t)c * NSP + n0 + ch * 4);
  }
#pragma unroll
  for (int i = 0; i < 8; ++i) {
    int idx = t + 256 * i;
    int o = idx >> 5, col = (idx & 31) * 4;
    float4 wv = *(const float4*)(Wz + o * CH + col);
    unsigned int p0 = (unsigned int)f2bf(wv.x) | ((unsigned int)f2bf(wv.y) << 16);
    unsigned int p1 = (unsigned int)f2bf(wv.z) | ((unsigned int)f2bf(wv.w) << 16);
    *(unsigned int*)(&sW[o * LDW + col]) = p0;
    *(unsigned int*)(&sW[o * LDW + col + 2]) = p1;
  }
  __syncthreads();

  const int wave = t >> 6, lane = t & 63;
  const int l15 = lane & 15, quad = lane >> 4;
  const int nw = wave * 16;
  s16x8 aq[4];
#pragma unroll
  for (int kc = 0; kc < 4; ++kc) {
#pragma unroll
    for (int j = 0; j < 8; ++j)
      aq[kc][j] = (short)f2bf(sxf[(kc * 32 + quad * 8 + j) * 65 + nw + l15]);
  }
  __syncthreads();

  unsigned short* ldsT = (unsigned short*)sxf;  // g transpose buffer [n][o] stride LDK

#pragma unroll
  for (int osub = 0; osub < 4; ++osub) {
    f32x4 acc = (f32x4){0.f, 0.f, 0.f, 0.f};
#pragma unroll
    for (int kc = 0; kc < 4; ++kc) {
      const unsigned short* wp = &sW[(osub * 16 + l15) * LDW + kc * 32 + quad * 8];
      s16x4 lo = *(const s16x4*)(wp);
      s16x4 hi = *(const s16x4*)(wp + 4);
      s16x8 bw = __builtin_shufflevector(lo, hi, 0, 1, 2, 3, 4, 5, 6, 7);
      acc = __builtin_amdgcn_mfma_f32_16x16x32_bf16(aq[kc], bw, acc, 0, 0, 0);
    }
    float bv = Bz[osub * 16 + l15];
    if (z < 2) {
      unsigned short* outp = (z == 0) ? thetaT : phiT;
#pragma unroll
      for (int r = 0; r < 4; ++r)
        outp[((size_t)b * NSP + n0 + nw + quad * 4 + r) * ICH + osub * 16 + l15] =
            f2bf((acc[r] + bv) * scl);
    } else {
#pragma unroll
      for (int r = 0; r < 4; ++r)
        ldsT[(nw + quad * 4 + r) * LDK + osub * 16 + l15] = f2bf(acc[r] + bv);
    }
  }
  if (z == 2) {
    __syncthreads();
    int o = t >> 2, chunk = t & 3;
    unsigned short vv[16];
#pragma unroll
    for (int jj = 0; jj < 16; ++jj) vv[jj] = ldsT[(chunk * 16 + jj) * LDK + o];
    unsigned int words[8];
#pragma unroll
    for (int i = 0; i < 8; ++i)
      words[i] = (unsigned int)vv[2 * i] | ((unsigned int)vv[2 * i + 1] << 16);
    unsigned short* gp = gout + ((size_t)b * ICH + o) * NSP + n0 + chunk * 16;
    *(u32x4*)(gp) = (u32x4){words[0], words[1], words[2], words[3]};
    *(u32x4*)(gp + 8) = (u32x4){words[4], words[5], words[6], words[7]};
  }
}

// ---------------- Kernel 2: flash attention partials -------------------------
// 2 waves/block, q-tile 128 (64 q/wave), K-tile 64, K-split 16.
// exp2 path (theta pre-scaled); trunc bf16 P; row-sum l via ones-column MFMA.
// Epilogue stages O through LDS -> full-line coalesced stores (R3 lesson:
// scalar bf16 stores caused 4x write amplification + RMW fetches).
__global__ __launch_bounds__(128, 4) void k_attn(
    const unsigned short* __restrict__ thetaT,
    const unsigned short* __restrict__ phiT,
    const unsigned short* __restrict__ gmat,
    unsigned short* __restrict__ Opart, float* __restrict__ lpart)
{
  __shared__ unsigned short ldsK[64 * LDK];
  __shared__ unsigned short ldsV[64 * LDK];
  __shared__ unsigned short ldsP[2][16 * LDK];   // per-wave 16-row P / O-staging buffer
  const int qt = blockIdx.x, b = blockIdx.y, seg = blockIdx.z;
  const int t = threadIdx.x;
  const int wave = t >> 6, lane = t & 63;
  const int l15 = lane & 15, quad = lane >> 4;
  const int q0 = qt * 128 + wave * 64;

  s16x8 aq[4][2];
  const unsigned short* th = thetaT + ((size_t)b * NSP + q0) * ICH;
#pragma unroll
  for (int qs = 0; qs < 4; ++qs)
#pragma unroll
    for (int ks = 0; ks < 2; ++ks)
      aq[qs][ks] = __builtin_bit_cast(s16x8,
          *(const u32x4*)(th + (qs * 16 + l15) * ICH + ks * 32 + quad * 8));

  f32x4 Oacc[4][4];
  f32x4 lacc[4];
#pragma unroll
  for (int i = 0; i < 4; ++i) {
    lacc[i] = (f32x4){0.f, 0.f, 0.f, 0.f};
#pragma unroll
    for (int j = 0; j < 4; ++j) Oacc[i][j] = (f32x4){0.f, 0.f, 0.f, 0.f};
  }

  // ones-column B-frag: B[k][n]=(n==0) -> C col 0 = row-sum of A
  s16x8 bones;
  {
    short v = (l15 == 0) ? (short)0x3F80 : (short)0;
#pragma unroll
    for (int j = 0; j < 8; ++j) bones[j] = v;
  }

  const unsigned short* ph = phiT + (size_t)b * NSP * ICH;
  const unsigned short* gb = gmat + (size_t)b * ICH * NSP;
  const int k0 = seg * SEGK;

  for (int kt = 0; kt < SEGK / 64; ++kt) {
    const int key0 = k0 + kt * 64;
    __syncthreads();
    // stage K[key][d] and V^T[d][key]; 1024 16B chunks over 128 threads
#pragma unroll
    for (int i = 0; i < 8; ++i) {
      int idx = t + 128 * i;
      int rr = (idx >> 3) & 63, c8 = (idx & 7) * 8;
      if (idx < 512)
        *(u32x4*)(&ldsK[rr * LDK + c8]) =
            *(const u32x4*)(ph + (size_t)(key0 + rr) * ICH + c8);
      else
        *(u32x4*)(&ldsV[rr * LDK + c8]) =
            *(const u32x4*)(gb + (size_t)rr * NSP + key0 + c8);
    }
    __syncthreads();

    s16x8 bk[4][2];
#pragma unroll
    for (int kc = 0; kc < 4; ++kc)
#pragma unroll
      for (int ks = 0; ks < 2; ++ks)
        bk[kc][ks] = *(const s16x8*)(&ldsK[(kc * 16 + l15) * LDK + ks * 32 + quad * 8]);
    s16x8 bv[2][4];
#pragma unroll
    for (int ks = 0; ks < 2; ++ks)
#pragma unroll
      for (int ds = 0; ds < 4; ++ds)
        bv[ks][ds] = *(const s16x8*)(&ldsV[(ds * 16 + l15) * LDK + ks * 32 + quad * 8]);

    unsigned short* myP = &ldsP[wave][0];
#pragma unroll
    for (int qs = 0; qs < 4; ++qs) {
#pragma unroll
      for (int kc = 0; kc < 4; ++kc) {
        f32x4 sacc = (f32x4){0.f, 0.f, 0.f, 0.f};
        sacc = __builtin_amdgcn_mfma_f32_16x16x32_bf16(aq[qs][0], bk[kc][0], sacc, 0, 0, 0);
        sacc = __builtin_amdgcn_mfma_f32_16x16x32_bf16(aq[qs][1], bk[kc][1], sacc, 0, 0, 0);
#pragma unroll
        for (int r = 0; r < 4; ++r) {
          float e = exp2f(sacc[r]);        // theta carries log2(e)
          myP[(quad * 4 + r) * LDK + kc * 16 + l15] =
              (unsigned short)(__builtin_bit_cast(unsigned int, e) >> 16);  // trunc bf16
        }
      }
      // consume P immediately (wave-private LDS, in-order)
#pragma unroll
      for (int ks = 0; ks < 2; ++ks) {
        s16x8 ap = *(const s16x8*)(&myP[l15 * LDK + ks * 32 + quad * 8]);
        lacc[qs] = __builtin_amdgcn_mfma_f32_16x16x32_bf16(ap, bones, lacc[qs], 0, 0, 0);
#pragma unroll
        for (int ds = 0; ds < 4; ++ds)
          Oacc[qs][ds] = __builtin_amdgcn_mfma_f32_16x16x32_bf16(ap, bv[ks][ds], Oacc[qs][ds], 0, 0, 0);
      }
    }
  }

  // epilogue: O -> LDS (C-layout) -> coalesced full-line bf16 stores
  unsigned short* Ob = Opart + (((size_t)seg * NB + b) * NSP + q0) * ICH;
  unsigned short* myP = &ldsP[wave][0];
#pragma unroll
  for (int qs = 0; qs < 4; ++qs) {
#pragma unroll
    for (int ds = 0; ds < 4; ++ds)
#pragma unroll
      for (int r = 0; r < 4; ++r)
        myP[(quad * 4 + r) * LDK + ds * 16 + l15] = f2bf(Oacc[qs][ds][r]);
    // lane -> row=lane>>2 (16 rows), 32B chunk=(lane&3); wave writes 2 KB contiguous
    int row = lane >> 2, ch = (lane & 3) * 16;
    u32x4 w0 = *(const u32x4*)(&myP[row * LDK + ch]);
    u32x4 w1 = *(const u32x4*)(&myP[row * LDK + ch + 8]);
    *(u32x4*)(Ob + (qs * 16 + row) * ICH + ch) = w0;
    *(u32x4*)(Ob + (qs * 16 + row) * ICH + ch + 8) = w1;
  }
  if (l15 == 0) {
    float* lb = lpart + ((size_t)seg * NB + b) * NSP + q0;
#pragma unroll
    for (int qs = 0; qs < 4; ++qs)
#pragma unroll
      for (int r = 0; r < 4; ++r)
        lb[qs * 16 + quad * 4 + r] = lacc[qs][r];
  }
}

// ---------------- Kernel 3a: combine partials + W-proj + stats ---------------
// 2 waves/block; wave: 16 n rows x all 128 co
__global__ __launch_bounds__(128) void k_wy(
    const unsigned short* __restrict__ Opart, const float* __restrict__ lpart,
    const float* __restrict__ Ww,
    float* __restrict__ WyT, float* __restrict__ stat)
{
  const int b = blockIdx.y, nt = blockIdx.x;   // nt 0..127
  const int t = threadIdx.x;
  const int wave = t >> 6, lane = t & 63;
  const int l15 = lane & 15, quad = lane >> 4;
  const int n0 = nt * 32 + wave * 16;
  // softmax denominator for row n0+l15
  float ls = 0.f;
#pragma unroll
  for (int s = 0; s < KSPLIT; ++s)
    ls += lpart[((size_t)s * NB + b) * NSP + n0 + l15];
  float inv = 1.0f / ls;
  // combine O partials -> y A-frags
  s16x8 ay[2];
#pragma unroll
  for (int ks = 0; ks < 2; ++ks) {
    float acc8[8];
#pragma unroll
    for (int j = 0; j < 8; ++j) acc8[j] = 0.f;
#pragma unroll
    for (int s = 0; s < KSPLIT; ++s) {
      const unsigned short* op =
          Opart + (((size_t)s * NB + b) * NSP + n0 + l15) * ICH + ks * 32 + quad * 8;
      u32x4 raw = *(const u32x4*)op;
#pragma unroll
      for (int w2 = 0; w2 < 4; ++w2) {
        unsigned int u = raw[w2];
        acc8[2 * w2]     += __builtin_bit_cast(float, u << 16);
        acc8[2 * w2 + 1] += __builtin_bit_cast(float, u & 0xFFFF0000u);
      }
    }
#pragma unroll
    for (int j = 0; j < 8; ++j) ay[ks][j] = (short)f2bf(acc8[j] * inv);
  }
  // Ww B-frags
  s16x8 bw[8][2];
#pragma unroll
  for (int cc = 0; cc < 8; ++cc)
#pragma unroll
    for (int ks = 0; ks < 2; ++ks) {
      const float* wp = Ww + (cc * 16 + l15) * ICH + ks * 32 + quad * 8;
      s16x8 e;
#pragma unroll
      for (int j = 0; j < 8; ++j) e[j] = (short)f2bf(wp[j]);
      bw[cc][ks] = e;
    }
  float sums[8], sq[8];
#pragma unroll
  for (int cc = 0; cc < 8; ++cc) { sums[cc] = 0.f; sq[cc] = 0.f; }
#pragma unroll
  for (int cc = 0; cc < 8; ++cc) {
    f32x4 acc = (f32x4){0.f, 0.f, 0.f, 0.f};
    acc = __builtin_amdgcn_mfma_f32_16x16x32_bf16(ay[0], bw[cc][0], acc, 0, 0, 0);
    acc = __builtin_amdgcn_mfma_f32_16x16x32_bf16(ay[1], bw[cc][1], acc, 0, 0, 0);
    float* wout = WyT + ((size_t)b * NSP + n0 + quad * 4) * CH + cc * 16 + l15;
#pragma unroll
    for (int r = 0; r < 4; ++r) {
      float v = acc[r];
      sums[cc] += v;
      sq[cc] += v * v;
      wout[r * CH] = v;
    }
  }
#pragma unroll
  for (int cc = 0; cc < 8; ++cc) {
    sums[cc] += __shfl_xor(sums[cc], 16, 64);
    sums[cc] += __shfl_xor(sums[cc], 32, 64);
    sq[cc] += __shfl_xor(sq[cc], 16, 64);
    sq[cc] += __shfl_xor(sq[cc], 32, 64);
  }
  if (quad == 0) {
#pragma unroll
    for (int cc = 0; cc < 8; ++cc) {
      atomicAdd(&stat[(b * CH + cc * 16 + l15) * 2 + 0], sums[cc]);
      atomicAdd(&stat[(b * CH + cc * 16 + l15) * 2 + 1], sq[cc]);
    }
  }
}

// ---------------- Kernel 3b: InstanceNorm + residual, out [B][C][N] ---------
__global__ __launch_bounds__(256) void k_norm(
    const float* __restrict__ WyT, const float* __restrict__ stat,
    const float* __restrict__ x, float* __restrict__ out)
{
  __shared__ float sWy[32 * 132];
  const int nt = blockIdx.x;        // 0..127
  const int b = blockIdx.y;
  const int t = threadIdx.x;
  const int n0 = nt * 32;
#pragma unroll
  for (int i = 0; i < 4; ++i) {
    int idx = t + 256 * i;
    int row = idx >> 5, c4 = idx & 31;
    *(float4*)(&sWy[row * 132 + c4 * 4]) =
        *(const float4*)(WyT + ((size_t)b * NSP + n0 + row) * CH + c4 * 4);
  }
  __syncthreads();
#pragma unroll
  for (int j = 0; j < 4; ++j) {
    int u = t + 256 * j;
    int co = u >> 3, nq = u & 7;
    float s = stat[(b * CH + co) * 2 + 0];
    float ss = stat[(b * CH + co) * 2 + 1];
    float mean = s * (1.f / NSP);
    float var = ss * (1.f / NSP) - mean * mean;
    float rs = rsqrtf(var + 1e-5f);
    float4 xv = *(const float4*)(x + (size_t)(b * CH + co) * NSP + n0 + nq * 4);
    float4 ov;
    ov.x = xv.x + (sWy[(nq * 4 + 0) * 132 + co] - mean) * rs;
    ov.y = xv.y + (sWy[(nq * 4 + 1) * 132 + co] - mean) * rs;
    ov.z = xv.z + (sWy[(nq * 4 + 2) * 132 + co] - mean) * rs;
    ov.w = xv.w + (sWy[(nq * 4 + 3) * 132 + co] - mean) * rs;
    *(float4*)(out + (size_t)(b * CH + co) * NSP + n0 + nq * 4) = ov;
  }
}

extern "C" void kernel_launch(void* const* d_in, const int* in_sizes, int n_in,
                              void* d_out, int out_size, void* d_ws, size_t ws_size,
                              hipStream_t stream)
{
  const float* x  = (const float*)d_in[0];
  const float* gw = (const float*)d_in[1];
  const float* gb = (const float*)d_in[2];
  const float* tw = (const float*)d_in[3];
  const float* tb = (const float*)d_in[4];
  const float* pw = (const float*)d_in[5];
  const float* pb = (const float*)d_in[6];
  const float* Ww = (const float*)d_in[7];
  // d_in[8] = W_b: canceled by InstanceNorm -> unused
  float* out = (float*)d_out;
  char* ws = (char*)d_ws;
  // workspace layout (~49.3 MB)
  unsigned short* thetaT = (unsigned short*)(ws);                        // 2 MB
  unsigned short* phiT   = (unsigned short*)(ws + (2ull << 20));         // 2 MB
  unsigned short* gmat   = (unsigned short*)(ws + (4ull << 20));         // 2 MB
  float* WyT   = (float*)(ws + (8ull << 20));                            // 8 MB
  float* stat  = (float*)(ws + (16ull << 20));                           // 4 KB
  float* lpart = (float*)(ws + (16ull << 20) + (1ull << 18));            // 1 MB
  unsigned short* Opart = (unsigned short*)(ws + (17ull << 20) + (1ull << 18)); // 32 MB

  hipMemsetAsync(stat, 0, NB * CH * 2 * sizeof(float), stream);
  k_proj<<<dim3(64, 4, 3), 256, 0, stream>>>(x, gw, gb, tw, tb, pw, pb, thetaT, phiT, gmat);
  k_attn<<<dim3(32, 4, KSPLIT), 128, 0, stream>>>(thetaT, phiT, gmat, Opart, lpart);
  k_wy<<<dim3(128, 4), 128, 0, stream>>>(Opart, lpart, Ww, WyT, stat);
  k_norm<<<dim3(128, 4), 256, 0, stream>>>(WyT, stat, x, out);
}

// Round 5
// 233.232 us; speedup vs baseline: 1.1639x; 1.1639x over previous
//
#include <hip/hip_runtime.h>
#include <math.h>

typedef __attribute__((ext_vector_type(4))) float f32x4;
typedef __attribute__((ext_vector_type(8))) short s16x8;
typedef __attribute__((ext_vector_type(4))) short s16x4;
typedef __attribute__((ext_vector_type(4))) unsigned int u32x4;

#define NB 4
#define CH 128
#define ICH 64
#define NSP 4096
#define KSPLIT 16
#define SEGK (NSP / KSPLIT)   // 256
#define LDK 72    // LDS row stride (bf16): 144 B, 16B-aligned, 2-way banks only
#define LDW 136   // k_proj W LDS stride

static __device__ __forceinline__ unsigned short f2bf(float f) {
  unsigned int u = __builtin_bit_cast(unsigned int, f);
  u += 0x7fffu + ((u >> 16) & 1u);   // RNE
  return (unsigned short)(u >> 16);
}

// ---------------- Kernel 1: one projection per block (MFMA) ------------------
// z=0: thetaT [B][N][IC] (pre-scaled by log2e); z=1: phiT [B][N][IC]; z=2: g [B][IC][N]
__global__ __launch_bounds__(256) void k_proj(
    const float* __restrict__ x,
    const float* __restrict__ gw, const float* __restrict__ gbias,
    const float* __restrict__ tw, const float* __restrict__ tbias,
    const float* __restrict__ pw, const float* __restrict__ pbias,
    unsigned short* __restrict__ thetaT, unsigned short* __restrict__ phiT,
    unsigned short* __restrict__ gout)
{
  __shared__ __align__(16) float sxf[CH * 65];
  __shared__ __align__(16) unsigned short sW[ICH * LDW];
  const int b = blockIdx.y, z = blockIdx.z;
  const int n0 = blockIdx.x * 64;
  const int t = threadIdx.x;
  const float* Wz = (z == 0) ? tw : (z == 1) ? pw : gw;
  const float* Bz = (z == 0) ? tbias : (z == 1) ? pbias : gbias;
  const float scl = (z == 0) ? 1.44269504f : 1.0f;   // fold log2(e) into theta
  const float* xb = x + (size_t)b * CH * NSP;
#pragma unroll
  for (int i = 0; i < 8; ++i) {
    int idx = t + 256 * i;
    int c = idx >> 4, ch = idx & 15;
    *(float4*)(sxf + c * 65 + ch * 4) = *(const float4*)(xb + (size_t)c * NSP + n0 + ch * 4);
  }
#pragma unroll
  for (int i = 0; i < 8; ++i) {
    int idx = t + 256 * i;
    int o = idx >> 5, col = (idx & 31) * 4;
    float4 wv = *(const float4*)(Wz + o * CH + col);
    unsigned int p0 = (unsigned int)f2bf(wv.x) | ((unsigned int)f2bf(wv.y) << 16);
    unsigned int p1 = (unsigned int)f2bf(wv.z) | ((unsigned int)f2bf(wv.w) << 16);
    *(unsigned int*)(&sW[o * LDW + col]) = p0;
    *(unsigned int*)(&sW[o * LDW + col + 2]) = p1;
  }
  __syncthreads();

  const int wave = t >> 6, lane = t & 63;
  const int l15 = lane & 15, quad = lane >> 4;
  const int nw = wave * 16;
  s16x8 aq[4];
#pragma unroll
  for (int kc = 0; kc < 4; ++kc) {
#pragma unroll
    for (int j = 0; j < 8; ++j)
      aq[kc][j] = (short)f2bf(sxf[(kc * 32 + quad * 8 + j) * 65 + nw + l15]);
  }
  __syncthreads();

  unsigned short* ldsT = (unsigned short*)sxf;  // g transpose buffer [n][o] stride LDK

#pragma unroll
  for (int osub = 0; osub < 4; ++osub) {
    f32x4 acc = (f32x4){0.f, 0.f, 0.f, 0.f};
#pragma unroll
    for (int kc = 0; kc < 4; ++kc) {
      const unsigned short* wp = &sW[(osub * 16 + l15) * LDW + kc * 32 + quad * 8];
      s16x4 lo = *(const s16x4*)(wp);
      s16x4 hi = *(const s16x4*)(wp + 4);
      s16x8 bw = __builtin_shufflevector(lo, hi, 0, 1, 2, 3, 4, 5, 6, 7);
      acc = __builtin_amdgcn_mfma_f32_16x16x32_bf16(aq[kc], bw, acc, 0, 0, 0);
    }
    float bv = Bz[osub * 16 + l15];
    if (z < 2) {
      unsigned short* outp = (z == 0) ? thetaT : phiT;
#pragma unroll
      for (int r = 0; r < 4; ++r)
        outp[((size_t)b * NSP + n0 + nw + quad * 4 + r) * ICH + osub * 16 + l15] =
            f2bf((acc[r] + bv) * scl);
    } else {
#pragma unroll
      for (int r = 0; r < 4; ++r)
        ldsT[(nw + quad * 4 + r) * LDK + osub * 16 + l15] = f2bf(acc[r] + bv);
    }
  }
  if (z == 2) {
    __syncthreads();
    int o = t >> 2, chunk = t & 3;
    unsigned short vv[16];
#pragma unroll
    for (int jj = 0; jj < 16; ++jj) vv[jj] = ldsT[(chunk * 16 + jj) * LDK + o];
    unsigned int words[8];
#pragma unroll
    for (int i = 0; i < 8; ++i)
      words[i] = (unsigned int)vv[2 * i] | ((unsigned int)vv[2 * i + 1] << 16);
    unsigned short* gp = gout + ((size_t)b * ICH + o) * NSP + n0 + chunk * 16;
    *(u32x4*)(gp) = (u32x4){words[0], words[1], words[2], words[3]};
    *(u32x4*)(gp + 8) = (u32x4){words[4], words[5], words[6], words[7]};
  }
}

// ---------------- Kernel 2: flash attention partials -------------------------
// 4 waves/block, q-tile 256 (64 q/wave), K-tile 64, K-split 16.
// exp2 path (theta pre-scaled); trunc bf16 P; row-sum l via ones-column MFMA.
// Epilogue: O staged via wave-private LDS, stored as 1-KB-dense instructions
// (R3/R4 lesson: every store instruction must tile full 64-B sectors itself;
// cross-instruction write-combining does NOT happen -> 4-10x write amp + RMW
// fetches that also destroy L3 absorption of phi/V re-reads).
__global__ __launch_bounds__(256, 4) void k_attn(
    const unsigned short* __restrict__ thetaT,
    const unsigned short* __restrict__ phiT,
    const unsigned short* __restrict__ gmat,
    unsigned short* __restrict__ Opart, float* __restrict__ lpart)
{
  __shared__ unsigned short ldsK[64 * LDK];
  __shared__ unsigned short ldsV[64 * LDK];
  __shared__ unsigned short ldsP[4][16 * LDK];   // per-wave 16-row P / O-staging buffer
  const int qt = blockIdx.x, b = blockIdx.y, seg = blockIdx.z;
  const int t = threadIdx.x;
  const int wave = t >> 6, lane = t & 63;
  const int l15 = lane & 15, quad = lane >> 4;
  const int q0 = qt * 256 + wave * 64;

  s16x8 aq[4][2];
  const unsigned short* th = thetaT + ((size_t)b * NSP + q0) * ICH;
#pragma unroll
  for (int qs = 0; qs < 4; ++qs)
#pragma unroll
    for (int ks = 0; ks < 2; ++ks)
      aq[qs][ks] = __builtin_bit_cast(s16x8,
          *(const u32x4*)(th + (qs * 16 + l15) * ICH + ks * 32 + quad * 8));

  f32x4 Oacc[4][4];
  f32x4 lacc[4];
#pragma unroll
  for (int i = 0; i < 4; ++i) {
    lacc[i] = (f32x4){0.f, 0.f, 0.f, 0.f};
#pragma unroll
    for (int j = 0; j < 4; ++j) Oacc[i][j] = (f32x4){0.f, 0.f, 0.f, 0.f};
  }

  // ones-column B-frag: B[k][n]=(n==0) -> C col 0 = row-sum of A
  s16x8 bones;
  {
    short v = (l15 == 0) ? (short)0x3F80 : (short)0;
#pragma unroll
    for (int j = 0; j < 8; ++j) bones[j] = v;
  }

  const unsigned short* ph = phiT + (size_t)b * NSP * ICH;
  const unsigned short* gb = gmat + (size_t)b * ICH * NSP;
  const int k0 = seg * SEGK;

  for (int kt = 0; kt < SEGK / 64; ++kt) {
    const int key0 = k0 + kt * 64;
    __syncthreads();
    // stage K[key][d] and V^T[d][key]; 1024 16B chunks over 256 threads
#pragma unroll
    for (int i = 0; i < 4; ++i) {
      int idx = t + 256 * i;
      int rr = (idx >> 3) & 63, c8 = (idx & 7) * 8;
      if (idx < 512)
        *(u32x4*)(&ldsK[rr * LDK + c8]) =
            *(const u32x4*)(ph + (size_t)(key0 + rr) * ICH + c8);
      else
        *(u32x4*)(&ldsV[rr * LDK + c8]) =
            *(const u32x4*)(gb + (size_t)rr * NSP + key0 + c8);
    }
    __syncthreads();

    s16x8 bk[4][2];
#pragma unroll
    for (int kc = 0; kc < 4; ++kc)
#pragma unroll
      for (int ks = 0; ks < 2; ++ks)
        bk[kc][ks] = *(const s16x8*)(&ldsK[(kc * 16 + l15) * LDK + ks * 32 + quad * 8]);
    s16x8 bv[2][4];
#pragma unroll
    for (int ks = 0; ks < 2; ++ks)
#pragma unroll
      for (int ds = 0; ds < 4; ++ds)
        bv[ks][ds] = *(const s16x8*)(&ldsV[(ds * 16 + l15) * LDK + ks * 32 + quad * 8]);

    unsigned short* myP = &ldsP[wave][0];
#pragma unroll
    for (int qs = 0; qs < 4; ++qs) {
#pragma unroll
      for (int kc = 0; kc < 4; ++kc) {
        f32x4 sacc = (f32x4){0.f, 0.f, 0.f, 0.f};
        sacc = __builtin_amdgcn_mfma_f32_16x16x32_bf16(aq[qs][0], bk[kc][0], sacc, 0, 0, 0);
        sacc = __builtin_amdgcn_mfma_f32_16x16x32_bf16(aq[qs][1], bk[kc][1], sacc, 0, 0, 0);
#pragma unroll
        for (int r = 0; r < 4; ++r) {
          float e = exp2f(sacc[r]);        // theta carries log2(e)
          myP[(quad * 4 + r) * LDK + kc * 16 + l15] =
              (unsigned short)(__builtin_bit_cast(unsigned int, e) >> 16);  // trunc bf16
        }
      }
      // consume P immediately (wave-private LDS, in-order)
#pragma unroll
      for (int ks = 0; ks < 2; ++ks) {
        s16x8 ap = *(const s16x8*)(&myP[l15 * LDK + ks * 32 + quad * 8]);
        lacc[qs] = __builtin_amdgcn_mfma_f32_16x16x32_bf16(ap, bones, lacc[qs], 0, 0, 0);
#pragma unroll
        for (int ds = 0; ds < 4; ++ds)
          Oacc[qs][ds] = __builtin_amdgcn_mfma_f32_16x16x32_bf16(ap, bv[ks][ds], Oacc[qs][ds], 0, 0, 0);
      }
    }
  }

  // epilogue: O -> wave-private LDS (C-layout) -> 1-KB-dense bf16 stores
  unsigned short* Ob = Opart + (((size_t)seg * NB + b) * NSP + q0) * ICH;
  unsigned short* myP = &ldsP[wave][0];
  const int erow = lane >> 3;            // 8 lanes per row
  const int ecol = (lane & 7) * 8;       // 16-B chunk per lane; 8 lanes = 128 B dense
#pragma unroll
  for (int qs = 0; qs < 4; ++qs) {
#pragma unroll
    for (int ds = 0; ds < 4; ++ds)
#pragma unroll
      for (int r = 0; r < 4; ++r)
        myP[(quad * 4 + r) * LDK + ds * 16 + l15] = f2bf(Oacc[qs][ds][r]);
    // rows 0-7 then 8-15: each instruction = 8 rows x 128 B contiguous = 1 KB dense
    u32x4 w0 = *(const u32x4*)(&myP[erow * LDK + ecol]);
    u32x4 w1 = *(const u32x4*)(&myP[(8 + erow) * LDK + ecol]);
    *(u32x4*)(Ob + (qs * 16 + erow) * ICH + ecol) = w0;
    *(u32x4*)(Ob + (qs * 16 + 8 + erow) * ICH + ecol) = w1;
  }
  // l: stage to LDS, one 256-B dense store per wave
  {
    float* myPf = (float*)myP;
    if (l15 == 0) {
#pragma unroll
      for (int qs = 0; qs < 4; ++qs)
#pragma unroll
        for (int r = 0; r < 4; ++r)
          myPf[qs * 16 + quad * 4 + r] = lacc[qs][r];
    }
    float* lb = lpart + ((size_t)seg * NB + b) * NSP + q0;
    lb[lane] = myPf[lane];
  }
}

// ---------------- Kernel 3a: combine partials + W-proj + stats ---------------
// 2 waves/block; wave: 16 n rows x all 128 co
__global__ __launch_bounds__(128) void k_wy(
    const unsigned short* __restrict__ Opart, const float* __restrict__ lpart,
    const float* __restrict__ Ww,
    float* __restrict__ WyT, float* __restrict__ stat)
{
  const int b = blockIdx.y, nt = blockIdx.x;   // nt 0..127
  const int t = threadIdx.x;
  const int wave = t >> 6, lane = t & 63;
  const int l15 = lane & 15, quad = lane >> 4;
  const int n0 = nt * 32 + wave * 16;
  // softmax denominator for row n0+l15
  float ls = 0.f;
#pragma unroll
  for (int s = 0; s < KSPLIT; ++s)
    ls += lpart[((size_t)s * NB + b) * NSP + n0 + l15];
  float inv = 1.0f / ls;
  // combine O partials -> y A-frags
  s16x8 ay[2];
#pragma unroll
  for (int ks = 0; ks < 2; ++ks) {
    float acc8[8];
#pragma unroll
    for (int j = 0; j < 8; ++j) acc8[j] = 0.f;
#pragma unroll
    for (int s = 0; s < KSPLIT; ++s) {
      const unsigned short* op =
          Opart + (((size_t)s * NB + b) * NSP + n0 + l15) * ICH + ks * 32 + quad * 8;
      u32x4 raw = *(const u32x4*)op;
#pragma unroll
      for (int w2 = 0; w2 < 4; ++w2) {
        unsigned int u = raw[w2];
        acc8[2 * w2]     += __builtin_bit_cast(float, u << 16);
        acc8[2 * w2 + 1] += __builtin_bit_cast(float, u & 0xFFFF0000u);
      }
    }
#pragma unroll
    for (int j = 0; j < 8; ++j) ay[ks][j] = (short)f2bf(acc8[j] * inv);
  }
  // Ww B-frags
  s16x8 bw[8][2];
#pragma unroll
  for (int cc = 0; cc < 8; ++cc)
#pragma unroll
    for (int ks = 0; ks < 2; ++ks) {
      const float* wp = Ww + (cc * 16 + l15) * ICH + ks * 32 + quad * 8;
      s16x8 e;
#pragma unroll
      for (int j = 0; j < 8; ++j) e[j] = (short)f2bf(wp[j]);
      bw[cc][ks] = e;
    }
  float sums[8], sq[8];
#pragma unroll
  for (int cc = 0; cc < 8; ++cc) { sums[cc] = 0.f; sq[cc] = 0.f; }
#pragma unroll
  for (int cc = 0; cc < 8; ++cc) {
    f32x4 acc = (f32x4){0.f, 0.f, 0.f, 0.f};
    acc = __builtin_amdgcn_mfma_f32_16x16x32_bf16(ay[0], bw[cc][0], acc, 0, 0, 0);
    acc = __builtin_amdgcn_mfma_f32_16x16x32_bf16(ay[1], bw[cc][1], acc, 0, 0, 0);
    float* wout = WyT + ((size_t)b * NSP + n0 + quad * 4) * CH + cc * 16 + l15;
#pragma unroll
    for (int r = 0; r < 4; ++r) {
      float v = acc[r];
      sums[cc] += v;
      sq[cc] += v * v;
      wout[r * CH] = v;
    }
  }
#pragma unroll
  for (int cc = 0; cc < 8; ++cc) {
    sums[cc] += __shfl_xor(sums[cc], 16, 64);
    sums[cc] += __shfl_xor(sums[cc], 32, 64);
    sq[cc] += __shfl_xor(sq[cc], 16, 64);
    sq[cc] += __shfl_xor(sq[cc], 32, 64);
  }
  if (quad == 0) {
#pragma unroll
    for (int cc = 0; cc < 8; ++cc) {
      atomicAdd(&stat[(b * CH + cc * 16 + l15) * 2 + 0], sums[cc]);
      atomicAdd(&stat[(b * CH + cc * 16 + l15) * 2 + 1], sq[cc]);
    }
  }
}

// ---------------- Kernel 3b: InstanceNorm + residual, out [B][C][N] ---------
__global__ __launch_bounds__(256) void k_norm(
    const float* __restrict__ WyT, const float* __restrict__ stat,
    const float* __restrict__ x, float* __restrict__ out)
{
  __shared__ float sWy[32 * 132];
  const int nt = blockIdx.x;        // 0..127
  const int b = blockIdx.y;
  const int t = threadIdx.x;
  const int n0 = nt * 32;
#pragma unroll
  for (int i = 0; i < 4; ++i) {
    int idx = t + 256 * i;
    int row = idx >> 5, c4 = idx & 31;
    *(float4*)(&sWy[row * 132 + c4 * 4]) =
        *(const float4*)(WyT + ((size_t)b * NSP + n0 + row) * CH + c4 * 4);
  }
  __syncthreads();
#pragma unroll
  for (int j = 0; j < 4; ++j) {
    int u = t + 256 * j;
    int co = u >> 3, nq = u & 7;
    float s = stat[(b * CH + co) * 2 + 0];
    float ss = stat[(b * CH + co) * 2 + 1];
    float mean = s * (1.f / NSP);
    float var = ss * (1.f / NSP) - mean * mean;
    float rs = rsqrtf(var + 1e-5f);
    float4 xv = *(const float4*)(x + (size_t)(b * CH + co) * NSP + n0 + nq * 4);
    float4 ov;
    ov.x = xv.x + (sWy[(nq * 4 + 0) * 132 + co] - mean) * rs;
    ov.y = xv.y + (sWy[(nq * 4 + 1) * 132 + co] - mean) * rs;
    ov.z = xv.z + (sWy[(nq * 4 + 2) * 132 + co] - mean) * rs;
    ov.w = xv.w + (sWy[(nq * 4 + 3) * 132 + co] - mean) * rs;
    *(float4*)(out + (size_t)(b * CH + co) * NSP + n0 + nq * 4) = ov;
  }
}

extern "C" void kernel_launch(void* const* d_in, const int* in_sizes, int n_in,
                              void* d_out, int out_size, void* d_ws, size_t ws_size,
                              hipStream_t stream)
{
  const float* x  = (const float*)d_in[0];
  const float* gw = (const float*)d_in[1];
  const float* gb = (const float*)d_in[2];
  const float* tw = (const float*)d_in[3];
  const float* tb = (const float*)d_in[4];
  const float* pw = (const float*)d_in[5];
  const float* pb = (const float*)d_in[6];
  const float* Ww = (const float*)d_in[7];
  // d_in[8] = W_b: canceled by InstanceNorm -> unused
  float* out = (float*)d_out;
  char* ws = (char*)d_ws;
  // workspace layout (~49.3 MB)
  unsigned short* thetaT = (unsigned short*)(ws);                        // 2 MB
  unsigned short* phiT   = (unsigned short*)(ws + (2ull << 20));         // 2 MB
  unsigned short* gmat   = (unsigned short*)(ws + (4ull << 20));         // 2 MB
  float* WyT   = (float*)(ws + (8ull << 20));                            // 8 MB
  float* stat  = (float*)(ws + (16ull << 20));                           // 4 KB
  float* lpart = (float*)(ws + (16ull << 20) + (1ull << 18));            // 1 MB
  unsigned short* Opart = (unsigned short*)(ws + (17ull << 20) + (1ull << 18)); // 32 MB

  hipMemsetAsync(stat, 0, NB * CH * 2 * sizeof(float), stream);
  k_proj<<<dim3(64, 4, 3), 256, 0, stream>>>(x, gw, gb, tw, tb, pw, pb, thetaT, phiT, gmat);
  k_attn<<<dim3(16, 4, KSPLIT), 256, 0, stream>>>(thetaT, phiT, gmat, Opart, lpart);
  k_wy<<<dim3(128, 4), 128, 0, stream>>>(Opart, lpart, Ww, WyT, stat);
  k_norm<<<dim3(128, 4), 256, 0, stream>>>(WyT, stat, x, out);
}

// Round 6
// 147.611 us; speedup vs baseline: 1.8390x; 1.5800x over previous
//
#include <hip/hip_runtime.h>
#include <math.h>

typedef __attribute__((ext_vector_type(4))) float f32x4;
typedef __attribute__((ext_vector_type(8))) short s16x8;
typedef __attribute__((ext_vector_type(4))) short s16x4;
typedef __attribute__((ext_vector_type(4))) unsigned int u32x4;

#define NB 4
#define CH 128
#define ICH 64
#define NSP 4096
#define KSPLIT 16
#define SEGK (NSP / KSPLIT)   // 256
#define LDK 72    // LDS row stride (bf16): 144 B, 16B-aligned, 2-way banks only
#define LDW 136   // k_proj W LDS stride

static __device__ __forceinline__ unsigned short f2bf(float f) {
  unsigned int u = __builtin_bit_cast(unsigned int, f);
  u += 0x7fffu + ((u >> 16) & 1u);   // RNE
  return (unsigned short)(u >> 16);
}

// ---------------- Kernel 1: one projection per block (MFMA) ------------------
// z=0: thetaT [B][N][IC] (pre-scaled by log2e); z=1: phiT [B][N][IC]; z=2: g [B][IC][N]
__global__ __launch_bounds__(256) void k_proj(
    const float* __restrict__ x,
    const float* __restrict__ gw, const float* __restrict__ gbias,
    const float* __restrict__ tw, const float* __restrict__ tbias,
    const float* __restrict__ pw, const float* __restrict__ pbias,
    unsigned short* __restrict__ thetaT, unsigned short* __restrict__ phiT,
    unsigned short* __restrict__ gout)
{
  __shared__ __align__(16) float sxf[CH * 65];
  __shared__ __align__(16) unsigned short sW[ICH * LDW];
  const int b = blockIdx.y, z = blockIdx.z;
  const int n0 = blockIdx.x * 64;
  const int t = threadIdx.x;
  const float* Wz = (z == 0) ? tw : (z == 1) ? pw : gw;
  const float* Bz = (z == 0) ? tbias : (z == 1) ? pbias : gbias;
  const float scl = (z == 0) ? 1.44269504f : 1.0f;   // fold log2(e) into theta
  const float* xb = x + (size_t)b * CH * NSP;
#pragma unroll
  for (int i = 0; i < 8; ++i) {
    int idx = t + 256 * i;
    int c = idx >> 4, ch = idx & 15;
    *(float4*)(sxf + c * 65 + ch * 4) = *(const float4*)(xb + (size_t)c * NSP + n0 + ch * 4);
  }
#pragma unroll
  for (int i = 0; i < 8; ++i) {
    int idx = t + 256 * i;
    int o = idx >> 5, col = (idx & 31) * 4;
    float4 wv = *(const float4*)(Wz + o * CH + col);
    unsigned int p0 = (unsigned int)f2bf(wv.x) | ((unsigned int)f2bf(wv.y) << 16);
    unsigned int p1 = (unsigned int)f2bf(wv.z) | ((unsigned int)f2bf(wv.w) << 16);
    *(unsigned int*)(&sW[o * LDW + col]) = p0;
    *(unsigned int*)(&sW[o * LDW + col + 2]) = p1;
  }
  __syncthreads();

  const int wave = t >> 6, lane = t & 63;
  const int l15 = lane & 15, quad = lane >> 4;
  const int nw = wave * 16;
  s16x8 aq[4];
#pragma unroll
  for (int kc = 0; kc < 4; ++kc) {
#pragma unroll
    for (int j = 0; j < 8; ++j)
      aq[kc][j] = (short)f2bf(sxf[(kc * 32 + quad * 8 + j) * 65 + nw + l15]);
  }
  __syncthreads();

  unsigned short* ldsT = (unsigned short*)sxf;  // g transpose buffer [n][o] stride LDK

#pragma unroll
  for (int osub = 0; osub < 4; ++osub) {
    f32x4 acc = (f32x4){0.f, 0.f, 0.f, 0.f};
#pragma unroll
    for (int kc = 0; kc < 4; ++kc) {
      const unsigned short* wp = &sW[(osub * 16 + l15) * LDW + kc * 32 + quad * 8];
      s16x4 lo = *(const s16x4*)(wp);
      s16x4 hi = *(const s16x4*)(wp + 4);
      s16x8 bw = __builtin_shufflevector(lo, hi, 0, 1, 2, 3, 4, 5, 6, 7);
      acc = __builtin_amdgcn_mfma_f32_16x16x32_bf16(aq[kc], bw, acc, 0, 0, 0);
    }
    float bv = Bz[osub * 16 + l15];
    if (z < 2) {
      unsigned short* outp = (z == 0) ? thetaT : phiT;
#pragma unroll
      for (int r = 0; r < 4; ++r)
        outp[((size_t)b * NSP + n0 + nw + quad * 4 + r) * ICH + osub * 16 + l15] =
            f2bf((acc[r] + bv) * scl);
    } else {
#pragma unroll
      for (int r = 0; r < 4; ++r)
        ldsT[(nw + quad * 4 + r) * LDK + osub * 16 + l15] = f2bf(acc[r] + bv);
    }
  }
  if (z == 2) {
    __syncthreads();
    int o = t >> 2, chunk = t & 3;
    unsigned short vv[16];
#pragma unroll
    for (int jj = 0; jj < 16; ++jj) vv[jj] = ldsT[(chunk * 16 + jj) * LDK + o];
    unsigned int words[8];
#pragma unroll
    for (int i = 0; i < 8; ++i)
      words[i] = (unsigned int)vv[2 * i] | ((unsigned int)vv[2 * i + 1] << 16);
    unsigned short* gp = gout + ((size_t)b * ICH + o) * NSP + n0 + chunk * 16;
    *(u32x4*)(gp) = (u32x4){words[0], words[1], words[2], words[3]};
    *(u32x4*)(gp + 8) = (u32x4){words[4], words[5], words[6], words[7]};
  }
}

// ---------------- Kernel 2: flash attention partials -------------------------
// 4 waves/block, q-tile 256 (64 q/wave), K-tile 64, K-split 16.
// exp2 path (theta pre-scaled); trunc bf16 P; row-sum l via ones-column MFMA.
// launch_bounds(256, 2): live state ~200 unified regs/wave -> 2 waves/EU gives
// 256 regs, NO scratch spills. (R3-R5 lesson: tighter bounds (3-4 waves/EU)
// made the allocator spill ~40-70 regs; spill/reload in the kt loop generated
// 200-550 MB of TCC traffic and capped MfmaUtil at 6% despite 40% occupancy.)
__global__ __launch_bounds__(256, 2) void k_attn(
    const unsigned short* __restrict__ thetaT,
    const unsigned short* __restrict__ phiT,
    const unsigned short* __restrict__ gmat,
    unsigned short* __restrict__ Opart, float* __restrict__ lpart)
{
  __shared__ unsigned short ldsK[64 * LDK];
  __shared__ unsigned short ldsV[64 * LDK];
  __shared__ unsigned short ldsP[4][16 * LDK];   // per-wave 16-row P / O-staging buffer
  const int qt = blockIdx.x, b = blockIdx.y, seg = blockIdx.z;
  const int t = threadIdx.x;
  const int wave = t >> 6, lane = t & 63;
  const int l15 = lane & 15, quad = lane >> 4;
  const int q0 = qt * 256 + wave * 64;

  s16x8 aq[4][2];
  const unsigned short* th = thetaT + ((size_t)b * NSP + q0) * ICH;
#pragma unroll
  for (int qs = 0; qs < 4; ++qs)
#pragma unroll
    for (int ks = 0; ks < 2; ++ks)
      aq[qs][ks] = __builtin_bit_cast(s16x8,
          *(const u32x4*)(th + (qs * 16 + l15) * ICH + ks * 32 + quad * 8));

  f32x4 Oacc[4][4];
  f32x4 lacc[4];
#pragma unroll
  for (int i = 0; i < 4; ++i) {
    lacc[i] = (f32x4){0.f, 0.f, 0.f, 0.f};
#pragma unroll
    for (int j = 0; j < 4; ++j) Oacc[i][j] = (f32x4){0.f, 0.f, 0.f, 0.f};
  }

  // ones-column B-frag: B[k][n]=(n==0) -> C col 0 = row-sum of A
  s16x8 bones;
  {
    short v = (l15 == 0) ? (short)0x3F80 : (short)0;
#pragma unroll
    for (int j = 0; j < 8; ++j) bones[j] = v;
  }

  const unsigned short* ph = phiT + (size_t)b * NSP * ICH;
  const unsigned short* gb = gmat + (size_t)b * ICH * NSP;
  const int k0 = seg * SEGK;

  for (int kt = 0; kt < SEGK / 64; ++kt) {
    const int key0 = k0 + kt * 64;
    __syncthreads();
    // stage K[key][d] and V^T[d][key]; 1024 16B chunks over 256 threads
#pragma unroll
    for (int i = 0; i < 4; ++i) {
      int idx = t + 256 * i;
      int rr = (idx >> 3) & 63, c8 = (idx & 7) * 8;
      if (idx < 512)
        *(u32x4*)(&ldsK[rr * LDK + c8]) =
            *(const u32x4*)(ph + (size_t)(key0 + rr) * ICH + c8);
      else
        *(u32x4*)(&ldsV[rr * LDK + c8]) =
            *(const u32x4*)(gb + (size_t)rr * NSP + key0 + c8);
    }
    __syncthreads();

    s16x8 bk[4][2];
#pragma unroll
    for (int kc = 0; kc < 4; ++kc)
#pragma unroll
      for (int ks = 0; ks < 2; ++ks)
        bk[kc][ks] = *(const s16x8*)(&ldsK[(kc * 16 + l15) * LDK + ks * 32 + quad * 8]);
    s16x8 bv[2][4];
#pragma unroll
    for (int ks = 0; ks < 2; ++ks)
#pragma unroll
      for (int ds = 0; ds < 4; ++ds)
        bv[ks][ds] = *(const s16x8*)(&ldsV[(ds * 16 + l15) * LDK + ks * 32 + quad * 8]);

    unsigned short* myP = &ldsP[wave][0];
#pragma unroll
    for (int qs = 0; qs < 4; ++qs) {
#pragma unroll
      for (int kc = 0; kc < 4; ++kc) {
        f32x4 sacc = (f32x4){0.f, 0.f, 0.f, 0.f};
        sacc = __builtin_amdgcn_mfma_f32_16x16x32_bf16(aq[qs][0], bk[kc][0], sacc, 0, 0, 0);
        sacc = __builtin_amdgcn_mfma_f32_16x16x32_bf16(aq[qs][1], bk[kc][1], sacc, 0, 0, 0);
#pragma unroll
        for (int r = 0; r < 4; ++r) {
          float e = exp2f(sacc[r]);        // theta carries log2(e)
          myP[(quad * 4 + r) * LDK + kc * 16 + l15] =
              (unsigned short)(__builtin_bit_cast(unsigned int, e) >> 16);  // trunc bf16
        }
      }
      // consume P immediately (wave-private LDS, in-order)
#pragma unroll
      for (int ks = 0; ks < 2; ++ks) {
        s16x8 ap = *(const s16x8*)(&myP[l15 * LDK + ks * 32 + quad * 8]);
        lacc[qs] = __builtin_amdgcn_mfma_f32_16x16x32_bf16(ap, bones, lacc[qs], 0, 0, 0);
#pragma unroll
        for (int ds = 0; ds < 4; ++ds)
          Oacc[qs][ds] = __builtin_amdgcn_mfma_f32_16x16x32_bf16(ap, bv[ks][ds], Oacc[qs][ds], 0, 0, 0);
      }
    }
  }

  // epilogue: O -> wave-private LDS (C-layout) -> 1-KB-dense bf16 stores
  unsigned short* Ob = Opart + (((size_t)seg * NB + b) * NSP + q0) * ICH;
  unsigned short* myP = &ldsP[wave][0];
  const int erow = lane >> 3;            // 8 lanes per row
  const int ecol = (lane & 7) * 8;       // 16-B chunk per lane; 8 lanes = 128 B dense
#pragma unroll
  for (int qs = 0; qs < 4; ++qs) {
#pragma unroll
    for (int ds = 0; ds < 4; ++ds)
#pragma unroll
      for (int r = 0; r < 4; ++r)
        myP[(quad * 4 + r) * LDK + ds * 16 + l15] = f2bf(Oacc[qs][ds][r]);
    // rows 0-7 then 8-15: each instruction = 8 rows x 128 B contiguous = 1 KB dense
    u32x4 w0 = *(const u32x4*)(&myP[erow * LDK + ecol]);
    u32x4 w1 = *(const u32x4*)(&myP[(8 + erow) * LDK + ecol]);
    *(u32x4*)(Ob + (qs * 16 + erow) * ICH + ecol) = w0;
    *(u32x4*)(Ob + (qs * 16 + 8 + erow) * ICH + ecol) = w1;
  }
  // l: stage to LDS, one 256-B dense store per wave
  {
    float* myPf = (float*)myP;
    if (l15 == 0) {
#pragma unroll
      for (int qs = 0; qs < 4; ++qs)
#pragma unroll
        for (int r = 0; r < 4; ++r)
          myPf[qs * 16 + quad * 4 + r] = lacc[qs][r];
    }
    float* lb = lpart + ((size_t)seg * NB + b) * NSP + q0;
    lb[lane] = myPf[lane];
  }
}

// ---------------- Kernel 3a: combine partials + W-proj + stats ---------------
// 2 waves/block; wave: 16 n rows x all 128 co
__global__ __launch_bounds__(128) void k_wy(
    const unsigned short* __restrict__ Opart, const float* __restrict__ lpart,
    const float* __restrict__ Ww,
    float* __restrict__ WyT, float* __restrict__ stat)
{
  const int b = blockIdx.y, nt = blockIdx.x;   // nt 0..127
  const int t = threadIdx.x;
  const int wave = t >> 6, lane = t & 63;
  const int l15 = lane & 15, quad = lane >> 4;
  const int n0 = nt * 32 + wave * 16;
  // softmax denominator for row n0+l15
  float ls = 0.f;
#pragma unroll
  for (int s = 0; s < KSPLIT; ++s)
    ls += lpart[((size_t)s * NB + b) * NSP + n0 + l15];
  float inv = 1.0f / ls;
  // combine O partials -> y A-frags
  s16x8 ay[2];
#pragma unroll
  for (int ks = 0; ks < 2; ++ks) {
    float acc8[8];
#pragma unroll
    for (int j = 0; j < 8; ++j) acc8[j] = 0.f;
#pragma unroll
    for (int s = 0; s < KSPLIT; ++s) {
      const unsigned short* op =
          Opart + (((size_t)s * NB + b) * NSP + n0 + l15) * ICH + ks * 32 + quad * 8;
      u32x4 raw = *(const u32x4*)op;
#pragma unroll
      for (int w2 = 0; w2 < 4; ++w2) {
        unsigned int u = raw[w2];
        acc8[2 * w2]     += __builtin_bit_cast(float, u << 16);
        acc8[2 * w2 + 1] += __builtin_bit_cast(float, u & 0xFFFF0000u);
      }
    }
#pragma unroll
    for (int j = 0; j < 8; ++j) ay[ks][j] = (short)f2bf(acc8[j] * inv);
  }
  // Ww B-frags
  s16x8 bw[8][2];
#pragma unroll
  for (int cc = 0; cc < 8; ++cc)
#pragma unroll
    for (int ks = 0; ks < 2; ++ks) {
      const float* wp = Ww + (cc * 16 + l15) * ICH + ks * 32 + quad * 8;
      s16x8 e;
#pragma unroll
      for (int j = 0; j < 8; ++j) e[j] = (short)f2bf(wp[j]);
      bw[cc][ks] = e;
    }
  float sums[8], sq[8];
#pragma unroll
  for (int cc = 0; cc < 8; ++cc) { sums[cc] = 0.f; sq[cc] = 0.f; }
#pragma unroll
  for (int cc = 0; cc < 8; ++cc) {
    f32x4 acc = (f32x4){0.f, 0.f, 0.f, 0.f};
    acc = __builtin_amdgcn_mfma_f32_16x16x32_bf16(ay[0], bw[cc][0], acc, 0, 0, 0);
    acc = __builtin_amdgcn_mfma_f32_16x16x32_bf16(ay[1], bw[cc][1], acc, 0, 0, 0);
    float* wout = WyT + ((size_t)b * NSP + n0 + quad * 4) * CH + cc * 16 + l15;
#pragma unroll
    for (int r = 0; r < 4; ++r) {
      float v = acc[r];
      sums[cc] += v;
      sq[cc] += v * v;
      wout[r * CH] = v;
    }
  }
#pragma unroll
  for (int cc = 0; cc < 8; ++cc) {
    sums[cc] += __shfl_xor(sums[cc], 16, 64);
    sums[cc] += __shfl_xor(sums[cc], 32, 64);
    sq[cc] += __shfl_xor(sq[cc], 16, 64);
    sq[cc] += __shfl_xor(sq[cc], 32, 64);
  }
  if (quad == 0) {
#pragma unroll
    for (int cc = 0; cc < 8; ++cc) {
      atomicAdd(&stat[(b * CH + cc * 16 + l15) * 2 + 0], sums[cc]);
      atomicAdd(&stat[(b * CH + cc * 16 + l15) * 2 + 1], sq[cc]);
    }
  }
}

// ---------------- Kernel 3b: InstanceNorm + residual, out [B][C][N] ---------
__global__ __launch_bounds__(256) void k_norm(
    const float* __restrict__ WyT, const float* __restrict__ stat,
    const float* __restrict__ x, float* __restrict__ out)
{
  __shared__ float sWy[32 * 132];
  const int nt = blockIdx.x;        // 0..127
  const int b = blockIdx.y;
  const int t = threadIdx.x;
  const int n0 = nt * 32;
#pragma unroll
  for (int i = 0; i < 4; ++i) {
    int idx = t + 256 * i;
    int row = idx >> 5, c4 = idx & 31;
    *(float4*)(&sWy[row * 132 + c4 * 4]) =
        *(const float4*)(WyT + ((size_t)b * NSP + n0 + row) * CH + c4 * 4);
  }
  __syncthreads();
#pragma unroll
  for (int j = 0; j < 4; ++j) {
    int u = t + 256 * j;
    int co = u >> 3, nq = u & 7;
    float s = stat[(b * CH + co) * 2 + 0];
    float ss = stat[(b * CH + co) * 2 + 1];
    float mean = s * (1.f / NSP);
    float var = ss * (1.f / NSP) - mean * mean;
    float rs = rsqrtf(var + 1e-5f);
    float4 xv = *(const float4*)(x + (size_t)(b * CH + co) * NSP + n0 + nq * 4);
    float4 ov;
    ov.x = xv.x + (sWy[(nq * 4 + 0) * 132 + co] - mean) * rs;
    ov.y = xv.y + (sWy[(nq * 4 + 1) * 132 + co] - mean) * rs;
    ov.z = xv.z + (sWy[(nq * 4 + 2) * 132 + co] - mean) * rs;
    ov.w = xv.w + (sWy[(nq * 4 + 3) * 132 + co] - mean) * rs;
    *(float4*)(out + (size_t)(b * CH + co) * NSP + n0 + nq * 4) = ov;
  }
}

extern "C" void kernel_launch(void* const* d_in, const int* in_sizes, int n_in,
                              void* d_out, int out_size, void* d_ws, size_t ws_size,
                              hipStream_t stream)
{
  const float* x  = (const float*)d_in[0];
  const float* gw = (const float*)d_in[1];
  const float* gb = (const float*)d_in[2];
  const float* tw = (const float*)d_in[3];
  const float* tb = (const float*)d_in[4];
  const float* pw = (const float*)d_in[5];
  const float* pb = (const float*)d_in[6];
  const float* Ww = (const float*)d_in[7];
  // d_in[8] = W_b: canceled by InstanceNorm -> unused
  float* out = (float*)d_out;
  char* ws = (char*)d_ws;
  // workspace layout (~49.3 MB)
  unsigned short* thetaT = (unsigned short*)(ws);                        // 2 MB
  unsigned short* phiT   = (unsigned short*)(ws + (2ull << 20));         // 2 MB
  unsigned short* gmat   = (unsigned short*)(ws + (4ull << 20));         // 2 MB
  float* WyT   = (float*)(ws + (8ull << 20));                            // 8 MB
  float* stat  = (float*)(ws + (16ull << 20));                           // 4 KB
  float* lpart = (float*)(ws + (16ull << 20) + (1ull << 18));            // 1 MB
  unsigned short* Opart = (unsigned short*)(ws + (17ull << 20) + (1ull << 18)); // 32 MB

  hipMemsetAsync(stat, 0, NB * CH * 2 * sizeof(float), stream);
  k_proj<<<dim3(64, 4, 3), 256, 0, stream>>>(x, gw, gb, tw, tb, pw, pb, thetaT, phiT, gmat);
  k_attn<<<dim3(16, 4, KSPLIT), 256, 0, stream>>>(thetaT, phiT, gmat, Opart, lpart);
  k_wy<<<dim3(128, 4), 128, 0, stream>>>(Opart, lpart, Ww, WyT, stat);
  k_norm<<<dim3(128, 4), 256, 0, stream>>>(WyT, stat, x, out);
}

// Round 7
// 146.408 us; speedup vs baseline: 1.8541x; 1.0082x over previous
//
#include <hip/hip_runtime.h>
#include <math.h>

typedef __attribute__((ext_vector_type(4))) float f32x4;
typedef __attribute__((ext_vector_type(8))) short s16x8;
typedef __attribute__((ext_vector_type(4))) short s16x4;
typedef __attribute__((ext_vector_type(4))) unsigned int u32x4;
typedef __attribute__((ext_vector_type(2))) unsigned int u32x2;

#define NB 4
#define CH 128
#define ICH 64
#define NSP 4096
#define KSPLIT 8
#define SEGK (NSP / KSPLIT)   // 512
#define LDK 72    // LDS row stride (bf16): 144 B, 16B-aligned, 2-way banks only
#define LDW 136   // k_proj W LDS stride

static __device__ __forceinline__ unsigned short f2bf(float f) {
  unsigned int u = __builtin_bit_cast(unsigned int, f);
  u += 0x7fffu + ((u >> 16) & 1u);   // RNE
  return (unsigned short)(u >> 16);
}

// ---------------- Kernel 0: Ww fp32 -> bf16 (once) ---------------------------
__global__ __launch_bounds__(256) void k_wconv(
    const float* __restrict__ Ww, unsigned short* __restrict__ Wwb)
{
  int i = blockIdx.x * 256 + threadIdx.x;   // 2048 float4 chunks = 8192 floats
  float4 v = ((const float4*)Ww)[i];
  unsigned int p0 = (unsigned int)f2bf(v.x) | ((unsigned int)f2bf(v.y) << 16);
  unsigned int p1 = (unsigned int)f2bf(v.z) | ((unsigned int)f2bf(v.w) << 16);
  *(u32x2*)(Wwb + i * 4) = (u32x2){p0, p1};
}

// ---------------- Kernel 1: one projection per block (MFMA) ------------------
// z=0: thetaT [B][N][IC] (pre-scaled by log2e); z=1: phiT [B][N][IC]; z=2: g [B][IC][N]
__global__ __launch_bounds__(256) void k_proj(
    const float* __restrict__ x,
    const float* __restrict__ gw, const float* __restrict__ gbias,
    const float* __restrict__ tw, const float* __restrict__ tbias,
    const float* __restrict__ pw, const float* __restrict__ pbias,
    unsigned short* __restrict__ thetaT, unsigned short* __restrict__ phiT,
    unsigned short* __restrict__ gout)
{
  __shared__ __align__(16) float sxf[CH * 65];
  __shared__ __align__(16) unsigned short sW[ICH * LDW];
  const int b = blockIdx.y, z = blockIdx.z;
  const int n0 = blockIdx.x * 64;
  const int t = threadIdx.x;
  const float* Wz = (z == 0) ? tw : (z == 1) ? pw : gw;
  const float* Bz = (z == 0) ? tbias : (z == 1) ? pbias : gbias;
  const float scl = (z == 0) ? 1.44269504f : 1.0f;   // fold log2(e) into theta
  const float* xb = x + (size_t)b * CH * NSP;
#pragma unroll
  for (int i = 0; i < 8; ++i) {
    int idx = t + 256 * i;
    int c = idx >> 4, ch = idx & 15;
    *(float4*)(sxf + c * 65 + ch * 4) = *(const float4*)(xb + (size_t)c * NSP + n0 + ch * 4);
  }
#pragma unroll
  for (int i = 0; i < 8; ++i) {
    int idx = t + 256 * i;
    int o = idx >> 5, col = (idx & 31) * 4;
    float4 wv = *(const float4*)(Wz + o * CH + col);
    unsigned int p0 = (unsigned int)f2bf(wv.x) | ((unsigned int)f2bf(wv.y) << 16);
    unsigned int p1 = (unsigned int)f2bf(wv.z) | ((unsigned int)f2bf(wv.w) << 16);
    *(unsigned int*)(&sW[o * LDW + col]) = p0;
    *(unsigned int*)(&sW[o * LDW + col + 2]) = p1;
  }
  __syncthreads();

  const int wave = t >> 6, lane = t & 63;
  const int l15 = lane & 15, quad = lane >> 4;
  const int nw = wave * 16;
  s16x8 aq[4];
#pragma unroll
  for (int kc = 0; kc < 4; ++kc) {
#pragma unroll
    for (int j = 0; j < 8; ++j)
      aq[kc][j] = (short)f2bf(sxf[(kc * 32 + quad * 8 + j) * 65 + nw + l15]);
  }
  __syncthreads();

  unsigned short* ldsT = (unsigned short*)sxf;  // g transpose buffer [n][o] stride LDK

#pragma unroll
  for (int osub = 0; osub < 4; ++osub) {
    f32x4 acc = (f32x4){0.f, 0.f, 0.f, 0.f};
#pragma unroll
    for (int kc = 0; kc < 4; ++kc) {
      const unsigned short* wp = &sW[(osub * 16 + l15) * LDW + kc * 32 + quad * 8];
      s16x4 lo = *(const s16x4*)(wp);
      s16x4 hi = *(const s16x4*)(wp + 4);
      s16x8 bw = __builtin_shufflevector(lo, hi, 0, 1, 2, 3, 4, 5, 6, 7);
      acc = __builtin_amdgcn_mfma_f32_16x16x32_bf16(aq[kc], bw, acc, 0, 0, 0);
    }
    float bv = Bz[osub * 16 + l15];
    if (z < 2) {
      unsigned short* outp = (z == 0) ? thetaT : phiT;
#pragma unroll
      for (int r = 0; r < 4; ++r)
        outp[((size_t)b * NSP + n0 + nw + quad * 4 + r) * ICH + osub * 16 + l15] =
            f2bf((acc[r] + bv) * scl);
    } else {
#pragma unroll
      for (int r = 0; r < 4; ++r)
        ldsT[(nw + quad * 4 + r) * LDK + osub * 16 + l15] = f2bf(acc[r] + bv);
    }
  }
  if (z == 2) {
    __syncthreads();
    int o = t >> 2, chunk = t & 3;
    unsigned short vv[16];
#pragma unroll
    for (int jj = 0; jj < 16; ++jj) vv[jj] = ldsT[(chunk * 16 + jj) * LDK + o];
    unsigned int words[8];
#pragma unroll
    for (int i = 0; i < 8; ++i)
      words[i] = (unsigned int)vv[2 * i] | ((unsigned int)vv[2 * i + 1] << 16);
    unsigned short* gp = gout + ((size_t)b * ICH + o) * NSP + n0 + chunk * 16;
    *(u32x4*)(gp) = (u32x4){words[0], words[1], words[2], words[3]};
    *(u32x4*)(gp + 8) = (u32x4){words[4], words[5], words[6], words[7]};
  }
}

// ---------------- Kernel 2: flash attention partials -------------------------
// 4 waves/block, q-tile 128 (32 q/wave), K-tile 64, K-split 8.
// exp2 path (theta pre-scaled); trunc bf16 P; row-sum l via ones-column MFMA.
// Register budget: aq 16 + bk 32 + bv 32 + misc ~30 arch, Oacc+lacc 40 acc
// -> ~150 unified, fits 3 waves/EU (512/3=170) WITHOUT spills.
// (R5 lesson: overshooting waves/EU vs live state -> scratch spill traffic.)
__global__ __launch_bounds__(256, 3) void k_attn(
    const unsigned short* __restrict__ thetaT,
    const unsigned short* __restrict__ phiT,
    const unsigned short* __restrict__ gmat,
    unsigned short* __restrict__ Opart, float* __restrict__ lpart)
{
  __shared__ unsigned short ldsK[64 * LDK];
  __shared__ unsigned short ldsV[64 * LDK];
  __shared__ unsigned short ldsP[4][16 * LDK];   // per-wave 16-row P / O-staging buffer
  const int qt = blockIdx.x, b = blockIdx.y, seg = blockIdx.z;
  const int t = threadIdx.x;
  const int wave = t >> 6, lane = t & 63;
  const int l15 = lane & 15, quad = lane >> 4;
  const int q0 = qt * 128 + wave * 32;

  s16x8 aq[2][2];
  const unsigned short* th = thetaT + ((size_t)b * NSP + q0) * ICH;
#pragma unroll
  for (int qs = 0; qs < 2; ++qs)
#pragma unroll
    for (int ks = 0; ks < 2; ++ks)
      aq[qs][ks] = __builtin_bit_cast(s16x8,
          *(const u32x4*)(th + (qs * 16 + l15) * ICH + ks * 32 + quad * 8));

  f32x4 Oacc[2][4];
  f32x4 lacc[2];
#pragma unroll
  for (int i = 0; i < 2; ++i) {
    lacc[i] = (f32x4){0.f, 0.f, 0.f, 0.f};
#pragma unroll
    for (int j = 0; j < 4; ++j) Oacc[i][j] = (f32x4){0.f, 0.f, 0.f, 0.f};
  }

  // ones-column B-frag: B[k][n]=(n==0) -> C col 0 = row-sum of A
  s16x8 bones;
  {
    short v = (l15 == 0) ? (short)0x3F80 : (short)0;
#pragma unroll
    for (int j = 0; j < 8; ++j) bones[j] = v;
  }

  const unsigned short* ph = phiT + (size_t)b * NSP * ICH;
  const unsigned short* gb = gmat + (size_t)b * ICH * NSP;
  const int k0 = seg * SEGK;

  for (int kt = 0; kt < SEGK / 64; ++kt) {
    const int key0 = k0 + kt * 64;
    __syncthreads();
    // stage K[key][d] and V^T[d][key]; 1024 16B chunks over 256 threads
#pragma unroll
    for (int i = 0; i < 4; ++i) {
      int idx = t + 256 * i;
      int rr = (idx >> 3) & 63, c8 = (idx & 7) * 8;
      if (idx < 512)
        *(u32x4*)(&ldsK[rr * LDK + c8]) =
            *(const u32x4*)(ph + (size_t)(key0 + rr) * ICH + c8);
      else
        *(u32x4*)(&ldsV[rr * LDK + c8]) =
            *(const u32x4*)(gb + (size_t)rr * NSP + key0 + c8);
    }
    __syncthreads();

    s16x8 bk[4][2];
#pragma unroll
    for (int kc = 0; kc < 4; ++kc)
#pragma unroll
      for (int ks = 0; ks < 2; ++ks)
        bk[kc][ks] = *(const s16x8*)(&ldsK[(kc * 16 + l15) * LDK + ks * 32 + quad * 8]);
    s16x8 bv[2][4];
#pragma unroll
    for (int ks = 0; ks < 2; ++ks)
#pragma unroll
      for (int ds = 0; ds < 4; ++ds)
        bv[ks][ds] = *(const s16x8*)(&ldsV[(ds * 16 + l15) * LDK + ks * 32 + quad * 8]);

    unsigned short* myP = &ldsP[wave][0];
#pragma unroll
    for (int qs = 0; qs < 2; ++qs) {
#pragma unroll
      for (int kc = 0; kc < 4; ++kc) {
        f32x4 sacc = (f32x4){0.f, 0.f, 0.f, 0.f};
        sacc = __builtin_amdgcn_mfma_f32_16x16x32_bf16(aq[qs][0], bk[kc][0], sacc, 0, 0, 0);
        sacc = __builtin_amdgcn_mfma_f32_16x16x32_bf16(aq[qs][1], bk[kc][1], sacc, 0, 0, 0);
#pragma unroll
        for (int r = 0; r < 4; ++r) {
          float e = exp2f(sacc[r]);        // theta carries log2(e)
          myP[(quad * 4 + r) * LDK + kc * 16 + l15] =
              (unsigned short)(__builtin_bit_cast(unsigned int, e) >> 16);  // trunc bf16
        }
      }
      // consume P immediately (wave-private LDS, in-order)
#pragma unroll
      for (int ks = 0; ks < 2; ++ks) {
        s16x8 ap = *(const s16x8*)(&myP[l15 * LDK + ks * 32 + quad * 8]);
        lacc[qs] = __builtin_amdgcn_mfma_f32_16x16x32_bf16(ap, bones, lacc[qs], 0, 0, 0);
#pragma unroll
        for (int ds = 0; ds < 4; ++ds)
          Oacc[qs][ds] = __builtin_amdgcn_mfma_f32_16x16x32_bf16(ap, bv[ks][ds], Oacc[qs][ds], 0, 0, 0);
      }
    }
  }

  // epilogue: O -> wave-private LDS (C-layout) -> 1-KB-dense bf16 stores
  unsigned short* Ob = Opart + (((size_t)seg * NB + b) * NSP + q0) * ICH;
  unsigned short* myP = &ldsP[wave][0];
  const int erow = lane >> 3;            // 8 lanes per row
  const int ecol = (lane & 7) * 8;       // 16-B chunk per lane; 8 lanes = 128 B dense
#pragma unroll
  for (int qs = 0; qs < 2; ++qs) {
#pragma unroll
    for (int ds = 0; ds < 4; ++ds)
#pragma unroll
      for (int r = 0; r < 4; ++r)
        myP[(quad * 4 + r) * LDK + ds * 16 + l15] = f2bf(Oacc[qs][ds][r]);
    // rows 0-7 then 8-15: each instruction = 8 rows x 128 B contiguous = 1 KB dense
    u32x4 w0 = *(const u32x4*)(&myP[erow * LDK + ecol]);
    u32x4 w1 = *(const u32x4*)(&myP[(8 + erow) * LDK + ecol]);
    *(u32x4*)(Ob + (qs * 16 + erow) * ICH + ecol) = w0;
    *(u32x4*)(Ob + (qs * 16 + 8 + erow) * ICH + ecol) = w1;
  }
  // l: stage to LDS, one 128-B dense store per wave
  {
    float* myPf = (float*)myP;
    if (l15 == 0) {
#pragma unroll
      for (int qs = 0; qs < 2; ++qs)
#pragma unroll
        for (int r = 0; r < 4; ++r)
          myPf[qs * 16 + quad * 4 + r] = lacc[qs][r];
    }
    float* lb = lpart + ((size_t)seg * NB + b) * NSP + q0;
    if (lane < 32) lb[lane] = myPf[lane];
  }
}

// ---------------- Kernel 3a: combine partials + W-proj + stats ---------------
// 2 waves/block; wave: 16 n rows x all 128 co; Ww pre-converted to bf16 (Wwb)
__global__ __launch_bounds__(128) void k_wy(
    const unsigned short* __restrict__ Opart, const float* __restrict__ lpart,
    const unsigned short* __restrict__ Wwb,
    float* __restrict__ WyT, float* __restrict__ stat)
{
  const int b = blockIdx.y, nt = blockIdx.x;   // nt 0..127
  const int t = threadIdx.x;
  const int wave = t >> 6, lane = t & 63;
  const int l15 = lane & 15, quad = lane >> 4;
  const int n0 = nt * 32 + wave * 16;
  // softmax denominator for row n0+l15
  float ls = 0.f;
#pragma unroll
  for (int s = 0; s < KSPLIT; ++s)
    ls += lpart[((size_t)s * NB + b) * NSP + n0 + l15];
  float inv = 1.0f / ls;
  // combine O partials -> y A-frags
  s16x8 ay[2];
#pragma unroll
  for (int ks = 0; ks < 2; ++ks) {
    float acc8[8];
#pragma unroll
    for (int j = 0; j < 8; ++j) acc8[j] = 0.f;
#pragma unroll
    for (int s = 0; s < KSPLIT; ++s) {
      const unsigned short* op =
          Opart + (((size_t)s * NB + b) * NSP + n0 + l15) * ICH + ks * 32 + quad * 8;
      u32x4 raw = *(const u32x4*)op;
#pragma unroll
      for (int w2 = 0; w2 < 4; ++w2) {
        unsigned int u = raw[w2];
        acc8[2 * w2]     += __builtin_bit_cast(float, u << 16);
        acc8[2 * w2 + 1] += __builtin_bit_cast(float, u & 0xFFFF0000u);
      }
    }
#pragma unroll
    for (int j = 0; j < 8; ++j) ay[ks][j] = (short)f2bf(acc8[j] * inv);
  }
  // Ww B-frags: vector bf16 loads (R6 lesson: scalar fp32 + f2bf per thread
  // was ~512 VALU ops/thread)
  s16x8 bw[8][2];
#pragma unroll
  for (int cc = 0; cc < 8; ++cc)
#pragma unroll
    for (int ks = 0; ks < 2; ++ks)
      bw[cc][ks] = __builtin_bit_cast(s16x8,
          *(const u32x4*)(Wwb + (cc * 16 + l15) * ICH + ks * 32 + quad * 8));
  float sums[8], sq[8];
#pragma unroll
  for (int cc = 0; cc < 8; ++cc) { sums[cc] = 0.f; sq[cc] = 0.f; }
#pragma unroll
  for (int cc = 0; cc < 8; ++cc) {
    f32x4 acc = (f32x4){0.f, 0.f, 0.f, 0.f};
    acc = __builtin_amdgcn_mfma_f32_16x16x32_bf16(ay[0], bw[cc][0], acc, 0, 0, 0);
    acc = __builtin_amdgcn_mfma_f32_16x16x32_bf16(ay[1], bw[cc][1], acc, 0, 0, 0);
    float* wout = WyT + ((size_t)b * NSP + n0 + quad * 4) * CH + cc * 16 + l15;
#pragma unroll
    for (int r = 0; r < 4; ++r) {
      float v = acc[r];
      sums[cc] += v;
      sq[cc] += v * v;
      wout[r * CH] = v;
    }
  }
#pragma unroll
  for (int cc = 0; cc < 8; ++cc) {
    sums[cc] += __shfl_xor(sums[cc], 16, 64);
    sums[cc] += __shfl_xor(sums[cc], 32, 64);
    sq[cc] += __shfl_xor(sq[cc], 16, 64);
    sq[cc] += __shfl_xor(sq[cc], 32, 64);
  }
  if (quad == 0) {
#pragma unroll
    for (int cc = 0; cc < 8; ++cc) {
      atomicAdd(&stat[(b * CH + cc * 16 + l15) * 2 + 0], sums[cc]);
      atomicAdd(&stat[(b * CH + cc * 16 + l15) * 2 + 1], sq[cc]);
    }
  }
}

// ---------------- Kernel 3b: InstanceNorm + residual, out [B][C][N] ---------
__global__ __launch_bounds__(256) void k_norm(
    const float* __restrict__ WyT, const float* __restrict__ stat,
    const float* __restrict__ x, float* __restrict__ out)
{
  __shared__ float sWy[32 * 132];
  const int nt = blockIdx.x;        // 0..127
  const int b = blockIdx.y;
  const int t = threadIdx.x;
  const int n0 = nt * 32;
#pragma unroll
  for (int i = 0; i < 4; ++i) {
    int idx = t + 256 * i;
    int row = idx >> 5, c4 = idx & 31;
    *(float4*)(&sWy[row * 132 + c4 * 4]) =
        *(const float4*)(WyT + ((size_t)b * NSP + n0 + row) * CH + c4 * 4);
  }
  __syncthreads();
#pragma unroll
  for (int j = 0; j < 4; ++j) {
    int u = t + 256 * j;
    int co = u >> 3, nq = u & 7;
    float s = stat[(b * CH + co) * 2 + 0];
    float ss = stat[(b * CH + co) * 2 + 1];
    float mean = s * (1.f / NSP);
    float var = ss * (1.f / NSP) - mean * mean;
    float rs = rsqrtf(var + 1e-5f);
    float4 xv = *(const float4*)(x + (size_t)(b * CH + co) * NSP + n0 + nq * 4);
    float4 ov;
    ov.x = xv.x + (sWy[(nq * 4 + 0) * 132 + co] - mean) * rs;
    ov.y = xv.y + (sWy[(nq * 4 + 1) * 132 + co] - mean) * rs;
    ov.z = xv.z + (sWy[(nq * 4 + 2) * 132 + co] - mean) * rs;
    ov.w = xv.w + (sWy[(nq * 4 + 3) * 132 + co] - mean) * rs;
    *(float4*)(out + (size_t)(b * CH + co) * NSP + n0 + nq * 4) = ov;
  }
}

extern "C" void kernel_launch(void* const* d_in, const int* in_sizes, int n_in,
                              void* d_out, int out_size, void* d_ws, size_t ws_size,
                              hipStream_t stream)
{
  const float* x  = (const float*)d_in[0];
  const float* gw = (const float*)d_in[1];
  const float* gb = (const float*)d_in[2];
  const float* tw = (const float*)d_in[3];
  const float* tb = (const float*)d_in[4];
  const float* pw = (const float*)d_in[5];
  const float* pb = (const float*)d_in[6];
  const float* Ww = (const float*)d_in[7];
  // d_in[8] = W_b: canceled by InstanceNorm -> unused
  float* out = (float*)d_out;
  char* ws = (char*)d_ws;
  // workspace layout (~33 MB)
  unsigned short* thetaT = (unsigned short*)(ws);                        // 2 MB
  unsigned short* phiT   = (unsigned short*)(ws + (2ull << 20));         // 2 MB
  unsigned short* gmat   = (unsigned short*)(ws + (4ull << 20));         // 2 MB
  float* WyT   = (float*)(ws + (8ull << 20));                            // 8 MB
  float* stat  = (float*)(ws + (16ull << 20));                           // 4 KB
  unsigned short* Wwb = (unsigned short*)(ws + (16ull << 20) + 65536);   // 16 KB
  float* lpart = (float*)(ws + (16ull << 20) + (1ull << 19));            // 512 KB
  unsigned short* Opart = (unsigned short*)(ws + (17ull << 20));         // 16 MB

  hipMemsetAsync(stat, 0, NB * CH * 2 * sizeof(float), stream);
  k_wconv<<<dim3(8), 256, 0, stream>>>(Ww, Wwb);
  k_proj<<<dim3(64, 4, 3), 256, 0, stream>>>(x, gw, gb, tw, tb, pw, pb, thetaT, phiT, gmat);
  k_attn<<<dim3(32, 4, KSPLIT), 256, 0, stream>>>(thetaT, phiT, gmat, Opart, lpart);
  k_wy<<<dim3(128, 4), 128, 0, stream>>>(Opart, lpart, Wwb, WyT, stat);
  k_norm<<<dim3(128, 4), 256, 0, stream>>>(WyT, stat, x, out);
}

// Round 9
// 142.226 us; speedup vs baseline: 1.9086x; 1.0294x over previous
//
#include <hip/hip_runtime.h>
#include <math.h>

typedef __attribute__((ext_vector_type(4))) float f32x4;
typedef __attribute__((ext_vector_type(8))) short s16x8;
typedef __attribute__((ext_vector_type(4))) unsigned int u32x4;
typedef __attribute__((ext_vector_type(2))) unsigned int u32x2;

#define NB 4
#define CH 128
#define ICH 64
#define NSP 4096
#define KSPLIT 8
#define SEGK (NSP / KSPLIT)   // 512
#define LDK 72    // LDS row stride (bf16): 144 B, 16B-aligned, 2-way banks only

static __device__ __forceinline__ unsigned short f2bf(float f) {
  unsigned int u = __builtin_bit_cast(unsigned int, f);
  u += 0x7fffu + ((u >> 16) & 1u);   // RNE
  return (unsigned short)(u >> 16);
}

// ---------------- Kernel 0: all weights fp32 -> bf16, + zero stat ------------
// Wwb layout: [theta 8192][phi 8192][g 8192][W 8192] bf16 elems
__global__ __launch_bounds__(256) void k_wconv(
    const float* __restrict__ tw, const float* __restrict__ pw,
    const float* __restrict__ gw, const float* __restrict__ Ww,
    unsigned short* __restrict__ Wwb, float* __restrict__ stat)
{
  int i = blockIdx.x * 256 + threadIdx.x;   // 8192 threads x 1 float4 chunk
  int which = i >> 11;                      // 2048 chunks per matrix
  const float* src = (which == 0) ? tw : (which == 1) ? pw : (which == 2) ? gw : Ww;
  float4 v = ((const float4*)src)[i & 2047];
  unsigned int p0 = (unsigned int)f2bf(v.x) | ((unsigned int)f2bf(v.y) << 16);
  unsigned int p1 = (unsigned int)f2bf(v.z) | ((unsigned int)f2bf(v.w) << 16);
  *(u32x2*)(Wwb + i * 4) = (u32x2){p0, p1};
  if (blockIdx.x == 0) {                    // stat = 1024 floats = 256 float4
    float4 z = {0.f, 0.f, 0.f, 0.f};
    ((float4*)stat)[threadIdx.x] = z;
  }
}

// ---------------- Kernel 1: all 3 projections per block (MFMA) ---------------
// thetaT [B][N][IC] (pre-scaled by log2e); phiT [B][N][IC]; g [B][IC][N]
// Block: 128 thr (2 waves), 32 n; wave: 16 n x all C. A-frags straight from
// global x (per-quad 64-B-dense dword loads); W B-frags from bf16 global
// (cache-hot 48 KB); all stores staged via LDS to full-sector-dense insts.
__global__ __launch_bounds__(128) void k_proj(
    const float* __restrict__ x,
    const float* __restrict__ gbias, const float* __restrict__ tbias,
    const float* __restrict__ pbias,
    const unsigned short* __restrict__ Wwb,
    unsigned short* __restrict__ thetaT, unsigned short* __restrict__ phiT,
    unsigned short* __restrict__ gout)
{
  __shared__ __align__(16) unsigned short ldsT[32 * LDK];  // C-tile staging
  const int b = blockIdx.y;
  const int n0 = blockIdx.x * 32;
  const int t = threadIdx.x;
  const int wave = t >> 6, lane = t & 63;
  const int l15 = lane & 15, quad = lane >> 4;
  const int n = n0 + wave * 16 + l15;
  const float* xb = x + (size_t)b * CH * NSP;

  // A-frags: aq[kc] = bf16(x[kc*32+quad*8+j][n]); 16 lanes consecutive n ->
  // each inst = 4 quads x 64-B dense sectors; every element read exactly once
  s16x8 aq[4];
#pragma unroll
  for (int kc = 0; kc < 4; ++kc)
#pragma unroll
    for (int j = 0; j < 8; ++j)
      aq[kc][j] = (short)f2bf(xb[(size_t)(kc * 32 + quad * 8 + j) * NSP + n]);

  unsigned short* myT = &ldsT[wave * 16 * LDK];
  const int erow = lane >> 3, ecol = (lane & 7) * 8;   // dense-store mapping

#pragma unroll
  for (int z = 0; z < 3; ++z) {
    const float* Bz = (z == 0) ? tbias : (z == 1) ? pbias : gbias;
    const float scl = (z == 0) ? 1.44269504f : 1.0f;   // fold log2(e) into theta
    const unsigned short* Wz = Wwb + z * (ICH * CH);
#pragma unroll
    for (int osub = 0; osub < 4; ++osub) {
      f32x4 acc = (f32x4){0.f, 0.f, 0.f, 0.f};
#pragma unroll
      for (int kc = 0; kc < 4; ++kc) {
        s16x8 bw = __builtin_bit_cast(s16x8,
            *(const u32x4*)(Wz + (osub * 16 + l15) * CH + kc * 32 + quad * 8));
        acc = __builtin_amdgcn_mfma_f32_16x16x32_bf16(aq[kc], bw, acc, 0, 0, 0);
      }
      float bv = Bz[osub * 16 + l15];
#pragma unroll
      for (int r = 0; r < 4; ++r)
        myT[(quad * 4 + r) * LDK + osub * 16 + l15] = f2bf((acc[r] + bv) * scl);
    }
    if (z < 2) {
      // wave-private [16 n][64 o] -> two 1-KB-dense insts (8 rows x 128 B)
      unsigned short* outp = ((z == 0) ? thetaT : phiT) + ((size_t)b * NSP + n0 + wave * 16) * ICH;
      u32x4 w0 = *(const u32x4*)(&myT[erow * LDK + ecol]);
      u32x4 w1 = *(const u32x4*)(&myT[(8 + erow) * LDK + ecol]);
      *(u32x4*)(outp + erow * ICH + ecol) = w0;
      *(u32x4*)(outp + (8 + erow) * ICH + ecol) = w1;
    } else {
      // g: block-level transpose [32 n][64 o] -> [o][n] rows.
      // R8 BUG FIX: with 128 threads, o=t>>2 only covered o 0..31 -> half of
      // gmat stayed poison. Correct mapping: 2 insts/thread, inst (wave*2+jj):
      // o = inst*16 + (lane>>2), nch = (lane&3)*8 -> each inst = 16 o-rows x
      // 64 B fully dense (4 lanes x 16 B per row); covers all 64 o.
      __syncthreads();
#pragma unroll
      for (int jj = 0; jj < 2; ++jj) {
        int o = (wave * 2 + jj) * 16 + (lane >> 2);
        int nch = (lane & 3) * 8;
        unsigned short vv[8];
#pragma unroll
        for (int q2 = 0; q2 < 8; ++q2) vv[q2] = ldsT[(nch + q2) * LDK + o];
        unsigned int words[4];
#pragma unroll
        for (int i2 = 0; i2 < 4; ++i2)
          words[i2] = (unsigned int)vv[2 * i2] | ((unsigned int)vv[2 * i2 + 1] << 16);
        *(u32x4*)(gout + ((size_t)b * ICH + o) * NSP + n0 + nch) =
            (u32x4){words[0], words[1], words[2], words[3]};
      }
    }
  }
}

// ---------------- Kernel 2: flash attention partials -------------------------
// R6-proven shape: 4 waves/block, q-tile 256 (64 q/wave), K-tile 64, KSPLIT 8.
// exp2 path (theta pre-scaled); trunc bf16 P; row-sum l via ones-column MFMA.
// launch_bounds(256,2): ~200 unified regs live -> no spills (R5 lesson);
// grid 512 = exactly 2 blocks/CU co-resident.
__global__ __launch_bounds__(256, 2) void k_attn(
    const unsigned short* __restrict__ thetaT,
    const unsigned short* __restrict__ phiT,
    const unsigned short* __restrict__ gmat,
    unsigned short* __restrict__ Opart, float* __restrict__ lpart)
{
  __shared__ unsigned short ldsK[64 * LDK];
  __shared__ unsigned short ldsV[64 * LDK];
  __shared__ unsigned short ldsP[4][16 * LDK];   // per-wave 16-row P / O-staging
  const int qt = blockIdx.x, b = blockIdx.y, seg = blockIdx.z;
  const int t = threadIdx.x;
  const int wave = t >> 6, lane = t & 63;
  const int l15 = lane & 15, quad = lane >> 4;
  const int q0 = qt * 256 + wave * 64;

  s16x8 aq[4][2];
  const unsigned short* th = thetaT + ((size_t)b * NSP + q0) * ICH;
#pragma unroll
  for (int qs = 0; qs < 4; ++qs)
#pragma unroll
    for (int ks = 0; ks < 2; ++ks)
      aq[qs][ks] = __builtin_bit_cast(s16x8,
          *(const u32x4*)(th + (qs * 16 + l15) * ICH + ks * 32 + quad * 8));

  f32x4 Oacc[4][4];
  f32x4 lacc[4];
#pragma unroll
  for (int i = 0; i < 4; ++i) {
    lacc[i] = (f32x4){0.f, 0.f, 0.f, 0.f};
#pragma unroll
    for (int j = 0; j < 4; ++j) Oacc[i][j] = (f32x4){0.f, 0.f, 0.f, 0.f};
  }

  // ones-column B-frag: B[k][n]=(n==0) -> C col 0 = row-sum of A
  s16x8 bones;
  {
    short v = (l15 == 0) ? (short)0x3F80 : (short)0;
#pragma unroll
    for (int j = 0; j < 8; ++j) bones[j] = v;
  }

  const unsigned short* ph = phiT + (size_t)b * NSP * ICH;
  const unsigned short* gb = gmat + (size_t)b * ICH * NSP;
  const int k0 = seg * SEGK;

  for (int kt = 0; kt < SEGK / 64; ++kt) {
    const int key0 = k0 + kt * 64;
    __syncthreads();
    // stage K[key][d] and V^T[d][key]; 1024 16B chunks over 256 threads
#pragma unroll
    for (int i = 0; i < 4; ++i) {
      int idx = t + 256 * i;
      int rr = (idx >> 3) & 63, c8 = (idx & 7) * 8;
      if (idx < 512)
        *(u32x4*)(&ldsK[rr * LDK + c8]) =
            *(const u32x4*)(ph + (size_t)(key0 + rr) * ICH + c8);
      else
        *(u32x4*)(&ldsV[rr * LDK + c8]) =
            *(const u32x4*)(gb + (size_t)rr * NSP + key0 + c8);
    }
    __syncthreads();

    s16x8 bk[4][2];
#pragma unroll
    for (int kc = 0; kc < 4; ++kc)
#pragma unroll
      for (int ks = 0; ks < 2; ++ks)
        bk[kc][ks] = *(const s16x8*)(&ldsK[(kc * 16 + l15) * LDK + ks * 32 + quad * 8]);
    s16x8 bv[2][4];
#pragma unroll
    for (int ks = 0; ks < 2; ++ks)
#pragma unroll
      for (int ds = 0; ds < 4; ++ds)
        bv[ks][ds] = *(const s16x8*)(&ldsV[(ds * 16 + l15) * LDK + ks * 32 + quad * 8]);

    unsigned short* myP = &ldsP[wave][0];
#pragma unroll
    for (int qs = 0; qs < 4; ++qs) {
#pragma unroll
      for (int kc = 0; kc < 4; ++kc) {
        f32x4 sacc = (f32x4){0.f, 0.f, 0.f, 0.f};
        sacc = __builtin_amdgcn_mfma_f32_16x16x32_bf16(aq[qs][0], bk[kc][0], sacc, 0, 0, 0);
        sacc = __builtin_amdgcn_mfma_f32_16x16x32_bf16(aq[qs][1], bk[kc][1], sacc, 0, 0, 0);
#pragma unroll
        for (int r = 0; r < 4; ++r) {
          float e = exp2f(sacc[r]);        // theta carries log2(e)
          myP[(quad * 4 + r) * LDK + kc * 16 + l15] =
              (unsigned short)(__builtin_bit_cast(unsigned int, e) >> 16);  // trunc bf16
        }
      }
      // consume P immediately (wave-private LDS, in-order)
#pragma unroll
      for (int ks = 0; ks < 2; ++ks) {
        s16x8 ap = *(const s16x8*)(&myP[l15 * LDK + ks * 32 + quad * 8]);
        lacc[qs] = __builtin_amdgcn_mfma_f32_16x16x32_bf16(ap, bones, lacc[qs], 0, 0, 0);
#pragma unroll
        for (int ds = 0; ds < 4; ++ds)
          Oacc[qs][ds] = __builtin_amdgcn_mfma_f32_16x16x32_bf16(ap, bv[ks][ds], Oacc[qs][ds], 0, 0, 0);
      }
    }
  }

  // epilogue: O -> wave-private LDS (C-layout) -> 1-KB-dense bf16 stores
  unsigned short* Ob = Opart + (((size_t)seg * NB + b) * NSP + q0) * ICH;
  unsigned short* myP = &ldsP[wave][0];
  const int erow = lane >> 3;            // 8 lanes per row
  const int ecol = (lane & 7) * 8;       // 16-B chunk; 8 lanes = 128 B dense
#pragma unroll
  for (int qs = 0; qs < 4; ++qs) {
#pragma unroll
    for (int ds = 0; ds < 4; ++ds)
#pragma unroll
      for (int r = 0; r < 4; ++r)
        myP[(quad * 4 + r) * LDK + ds * 16 + l15] = f2bf(Oacc[qs][ds][r]);
    u32x4 w0 = *(const u32x4*)(&myP[erow * LDK + ecol]);
    u32x4 w1 = *(const u32x4*)(&myP[(8 + erow) * LDK + ecol]);
    *(u32x4*)(Ob + (qs * 16 + erow) * ICH + ecol) = w0;
    *(u32x4*)(Ob + (qs * 16 + 8 + erow) * ICH + ecol) = w1;
  }
  // l: stage to LDS, one 256-B dense store per wave
  {
    float* myPf = (float*)myP;
    if (l15 == 0) {
#pragma unroll
      for (int qs = 0; qs < 4; ++qs)
#pragma unroll
        for (int r = 0; r < 4; ++r)
          myPf[qs * 16 + quad * 4 + r] = lacc[qs][r];
    }
    float* lb = lpart + ((size_t)seg * NB + b) * NSP + q0;
    lb[lane] = myPf[lane];
  }
}

// ---------------- Kernel 3a: combine partials + W-proj + stats ---------------
// 2 waves/block; wave: 16 n rows x all 128 co; Ww pre-converted bf16 (Wwb region 3)
__global__ __launch_bounds__(128) void k_wy(
    const unsigned short* __restrict__ Opart, const float* __restrict__ lpart,
    const unsigned short* __restrict__ Wwb,
    float* __restrict__ WyT, float* __restrict__ stat)
{
  const int b = blockIdx.y, nt = blockIdx.x;   // nt 0..127
  const int t = threadIdx.x;
  const int wave = t >> 6, lane = t & 63;
  const int l15 = lane & 15, quad = lane >> 4;
  const int n0 = nt * 32 + wave * 16;
  float ls = 0.f;
#pragma unroll
  for (int s = 0; s < KSPLIT; ++s)
    ls += lpart[((size_t)s * NB + b) * NSP + n0 + l15];
  float inv = 1.0f / ls;
  s16x8 ay[2];
#pragma unroll
  for (int ks = 0; ks < 2; ++ks) {
    float acc8[8];
#pragma unroll
    for (int j = 0; j < 8; ++j) acc8[j] = 0.f;
#pragma unroll
    for (int s = 0; s < KSPLIT; ++s) {
      const unsigned short* op =
          Opart + (((size_t)s * NB + b) * NSP + n0 + l15) * ICH + ks * 32 + quad * 8;
      u32x4 raw = *(const u32x4*)op;
#pragma unroll
      for (int w2 = 0; w2 < 4; ++w2) {
        unsigned int u = raw[w2];
        acc8[2 * w2]     += __builtin_bit_cast(float, u << 16);
        acc8[2 * w2 + 1] += __builtin_bit_cast(float, u & 0xFFFF0000u);
      }
    }
#pragma unroll
    for (int j = 0; j < 8; ++j) ay[ks][j] = (short)f2bf(acc8[j] * inv);
  }
  const unsigned short* Wb = Wwb + 3 * (ICH * CH);   // W region
  s16x8 bw[8][2];
#pragma unroll
  for (int cc = 0; cc < 8; ++cc)
#pragma unroll
    for (int ks = 0; ks < 2; ++ks)
      bw[cc][ks] = __builtin_bit_cast(s16x8,
          *(const u32x4*)(Wb + (cc * 16 + l15) * ICH + ks * 32 + quad * 8));
  float sums[8], sq[8];
#pragma unroll
  for (int cc = 0; cc < 8; ++cc) { sums[cc] = 0.f; sq[cc] = 0.f; }
#pragma unroll
  for (int cc = 0; cc < 8; ++cc) {
    f32x4 acc = (f32x4){0.f, 0.f, 0.f, 0.f};
    acc = __builtin_amdgcn_mfma_f32_16x16x32_bf16(ay[0], bw[cc][0], acc, 0, 0, 0);
    acc = __builtin_amdgcn_mfma_f32_16x16x32_bf16(ay[1], bw[cc][1], acc, 0, 0, 0);
    float* wout = WyT + ((size_t)b * NSP + n0 + quad * 4) * CH + cc * 16 + l15;
#pragma unroll
    for (int r = 0; r < 4; ++r) {
      float v = acc[r];
      sums[cc] += v;
      sq[cc] += v * v;
      wout[r * CH] = v;
    }
  }
#pragma unroll
  for (int cc = 0; cc < 8; ++cc) {
    sums[cc] += __shfl_xor(sums[cc], 16, 64);
    sums[cc] += __shfl_xor(sums[cc], 32, 64);
    sq[cc] += __shfl_xor(sq[cc], 16, 64);
    sq[cc] += __shfl_xor(sq[cc], 32, 64);
  }
  if (quad == 0) {
#pragma unroll
    for (int cc = 0; cc < 8; ++cc) {
      atomicAdd(&stat[(b * CH + cc * 16 + l15) * 2 + 0], sums[cc]);
      atomicAdd(&stat[(b * CH + cc * 16 + l15) * 2 + 1], sq[cc]);
    }
  }
}

// ---------------- Kernel 3b: InstanceNorm + residual, out [B][C][N] ---------
__global__ __launch_bounds__(256) void k_norm(
    const float* __restrict__ WyT, const float* __restrict__ stat,
    const float* __restrict__ x, float* __restrict__ out)
{
  __shared__ float sWy[32 * 132];
  const int nt = blockIdx.x;        // 0..127
  const int b = blockIdx.y;
  const int t = threadIdx.x;
  const int n0 = nt * 32;
#pragma unroll
  for (int i = 0; i < 4; ++i) {
    int idx = t + 256 * i;
    int row = idx >> 5, c4 = idx & 31;
    *(float4*)(&sWy[row * 132 + c4 * 4]) =
        *(const float4*)(WyT + ((size_t)b * NSP + n0 + row) * CH + c4 * 4);
  }
  __syncthreads();
#pragma unroll
  for (int j = 0; j < 4; ++j) {
    int u = t + 256 * j;
    int co = u >> 3, nq = u & 7;
    float s = stat[(b * CH + co) * 2 + 0];
    float ss = stat[(b * CH + co) * 2 + 1];
    float mean = s * (1.f / NSP);
    float var = ss * (1.f / NSP) - mean * mean;
    float rs = rsqrtf(var + 1e-5f);
    float4 xv = *(const float4*)(x + (size_t)(b * CH + co) * NSP + n0 + nq * 4);
    float4 ov;
    ov.x = xv.x + (sWy[(nq * 4 + 0) * 132 + co] - mean) * rs;
    ov.y = xv.y + (sWy[(nq * 4 + 1) * 132 + co] - mean) * rs;
    ov.z = xv.z + (sWy[(nq * 4 + 2) * 132 + co] - mean) * rs;
    ov.w = xv.w + (sWy[(nq * 4 + 3) * 132 + co] - mean) * rs;
    *(float4*)(out + (size_t)(b * CH + co) * NSP + n0 + nq * 4) = ov;
  }
}

extern "C" void kernel_launch(void* const* d_in, const int* in_sizes, int n_in,
                              void* d_out, int out_size, void* d_ws, size_t ws_size,
                              hipStream_t stream)
{
  const float* x  = (const float*)d_in[0];
  const float* gw = (const float*)d_in[1];
  const float* gb = (const float*)d_in[2];
  const float* tw = (const float*)d_in[3];
  const float* tb = (const float*)d_in[4];
  const float* pw = (const float*)d_in[5];
  const float* pb = (const float*)d_in[6];
  const float* Ww = (const float*)d_in[7];
  // d_in[8] = W_b: canceled by InstanceNorm -> unused
  float* out = (float*)d_out;
  char* ws = (char*)d_ws;
  // workspace layout (~33 MB)
  unsigned short* thetaT = (unsigned short*)(ws);                        // 2 MB
  unsigned short* phiT   = (unsigned short*)(ws + (2ull << 20));         // 2 MB
  unsigned short* gmat   = (unsigned short*)(ws + (4ull << 20));         // 2 MB
  float* WyT   = (float*)(ws + (8ull << 20));                            // 8 MB
  float* stat  = (float*)(ws + (16ull << 20));                           // 4 KB
  unsigned short* Wwb = (unsigned short*)(ws + (16ull << 20) + 65536);   // 64 KB
  float* lpart = (float*)(ws + (16ull << 20) + (1ull << 19));            // 512 KB
  unsigned short* Opart = (unsigned short*)(ws + (17ull << 20));         // 16 MB

  k_wconv<<<dim3(32), 256, 0, stream>>>(tw, pw, gw, Ww, Wwb, stat);
  k_proj<<<dim3(128, 4), 128, 0, stream>>>(x, gb, tb, pb, Wwb, thetaT, phiT, gmat);
  k_attn<<<dim3(16, 4, KSPLIT), 256, 0, stream>>>(thetaT, phiT, gmat, Opart, lpart);
  k_wy<<<dim3(128, 4), 128, 0, stream>>>(Opart, lpart, Wwb, WyT, stat);
  k_norm<<<dim3(128, 4), 256, 0, stream>>>(WyT, stat, x, out);
}

// Round 10
// 140.164 us; speedup vs baseline: 1.9367x; 1.0147x over previous
//
#include <hip/hip_runtime.h>
#include <math.h>

typedef __attribute__((ext_vector_type(4))) float f32x4;
typedef __attribute__((ext_vector_type(8))) short s16x8;
typedef __attribute__((ext_vector_type(4))) unsigned int u32x4;
typedef __attribute__((ext_vector_type(2))) unsigned int u32x2;

#define NB 4
#define CH 128
#define ICH 64
#define NSP 4096
#define KSPLIT 8
#define SEGK (NSP / KSPLIT)   // 512
#define LDK 72    // LDS row stride (bf16): 144 B, 16B-aligned, 2-way banks only

static __device__ __forceinline__ unsigned short f2bf(float f) {
  unsigned int u = __builtin_bit_cast(unsigned int, f);
  u += 0x7fffu + ((u >> 16) & 1u);   // RNE
  return (unsigned short)(u >> 16);
}

// ---------------- Kernel 0: all weights fp32 -> bf16, + zero stat ------------
// Wwb layout: [theta 8192][phi 8192][g 8192][W 8192] bf16 elems
__global__ __launch_bounds__(256) void k_wconv(
    const float* __restrict__ tw, const float* __restrict__ pw,
    const float* __restrict__ gw, const float* __restrict__ Ww,
    unsigned short* __restrict__ Wwb, float* __restrict__ stat)
{
  int i = blockIdx.x * 256 + threadIdx.x;   // 8192 threads x 1 float4 chunk
  int which = i >> 11;                      // 2048 chunks per matrix
  const float* src = (which == 0) ? tw : (which == 1) ? pw : (which == 2) ? gw : Ww;
  float4 v = ((const float4*)src)[i & 2047];
  unsigned int p0 = (unsigned int)f2bf(v.x) | ((unsigned int)f2bf(v.y) << 16);
  unsigned int p1 = (unsigned int)f2bf(v.z) | ((unsigned int)f2bf(v.w) << 16);
  *(u32x2*)(Wwb + i * 4) = (u32x2){p0, p1};
  if (blockIdx.x == 0) {                    // stat = 1024 floats = 256 float4
    float4 z = {0.f, 0.f, 0.f, 0.f};
    ((float4*)stat)[threadIdx.x] = z;
  }
}

// ---------------- Kernel 1: all 3 projections per block (MFMA) ---------------
// thetaT [B][N][IC] (pre-scaled by log2e); phiT [B][N][IC]; g [B][IC][N]
__global__ __launch_bounds__(128) void k_proj(
    const float* __restrict__ x,
    const float* __restrict__ gbias, const float* __restrict__ tbias,
    const float* __restrict__ pbias,
    const unsigned short* __restrict__ Wwb,
    unsigned short* __restrict__ thetaT, unsigned short* __restrict__ phiT,
    unsigned short* __restrict__ gout)
{
  __shared__ __align__(16) unsigned short ldsT[32 * LDK];  // C-tile staging
  const int b = blockIdx.y;
  const int n0 = blockIdx.x * 32;
  const int t = threadIdx.x;
  const int wave = t >> 6, lane = t & 63;
  const int l15 = lane & 15, quad = lane >> 4;
  const int n = n0 + wave * 16 + l15;
  const float* xb = x + (size_t)b * CH * NSP;

  s16x8 aq[4];
#pragma unroll
  for (int kc = 0; kc < 4; ++kc)
#pragma unroll
    for (int j = 0; j < 8; ++j)
      aq[kc][j] = (short)f2bf(xb[(size_t)(kc * 32 + quad * 8 + j) * NSP + n]);

  unsigned short* myT = &ldsT[wave * 16 * LDK];
  const int erow = lane >> 3, ecol = (lane & 7) * 8;

#pragma unroll
  for (int z = 0; z < 3; ++z) {
    const float* Bz = (z == 0) ? tbias : (z == 1) ? pbias : gbias;
    const float scl = (z == 0) ? 1.44269504f : 1.0f;
    const unsigned short* Wz = Wwb + z * (ICH * CH);
#pragma unroll
    for (int osub = 0; osub < 4; ++osub) {
      f32x4 acc = (f32x4){0.f, 0.f, 0.f, 0.f};
#pragma unroll
      for (int kc = 0; kc < 4; ++kc) {
        s16x8 bw = __builtin_bit_cast(s16x8,
            *(const u32x4*)(Wz + (osub * 16 + l15) * CH + kc * 32 + quad * 8));
        acc = __builtin_amdgcn_mfma_f32_16x16x32_bf16(aq[kc], bw, acc, 0, 0, 0);
      }
      float bv = Bz[osub * 16 + l15];
#pragma unroll
      for (int r = 0; r < 4; ++r)
        myT[(quad * 4 + r) * LDK + osub * 16 + l15] = f2bf((acc[r] + bv) * scl);
    }
    if (z < 2) {
      unsigned short* outp = ((z == 0) ? thetaT : phiT) + ((size_t)b * NSP + n0 + wave * 16) * ICH;
      u32x4 w0 = *(const u32x4*)(&myT[erow * LDK + ecol]);
      u32x4 w1 = *(const u32x4*)(&myT[(8 + erow) * LDK + ecol]);
      *(u32x4*)(outp + erow * ICH + ecol) = w0;
      *(u32x4*)(outp + (8 + erow) * ICH + ecol) = w1;
    } else {
      // g transpose: 2 insts/thread, each 16 o-rows x 64 B dense (R8 bug fixed)
      __syncthreads();
#pragma unroll
      for (int jj = 0; jj < 2; ++jj) {
        int o = (wave * 2 + jj) * 16 + (lane >> 2);
        int nch = (lane & 3) * 8;
        unsigned short vv[8];
#pragma unroll
        for (int q2 = 0; q2 < 8; ++q2) vv[q2] = ldsT[(nch + q2) * LDK + o];
        unsigned int words[4];
#pragma unroll
        for (int i2 = 0; i2 < 4; ++i2)
          words[i2] = (unsigned int)vv[2 * i2] | ((unsigned int)vv[2 * i2 + 1] << 16);
        *(u32x4*)(gout + ((size_t)b * ICH + o) * NSP + n0 + nch) =
            (u32x4){words[0], words[1], words[2], words[3]};
      }
    }
  }
}

// ---------------- Kernel 2: flash attention partials -------------------------
// R6 shape (4 waves, 64 q/wave, K-tile 64, KSPLIT 8, (256,2) no-spill) +
// DOUBLE-BUFFERED staging: prefetch tile kt+1 into registers at top of kt,
// compute kt from buf[cur], ds_write prefetch into buf[cur^1], ONE barrier/kt.
// Removes the load-latency + double-barrier drain from the critical path
// (R6-R9: 12.9k cyc/kt measured vs ~3k cyc of work -> stall-dominated).
__global__ __launch_bounds__(256, 2) void k_attn(
    const unsigned short* __restrict__ thetaT,
    const unsigned short* __restrict__ phiT,
    const unsigned short* __restrict__ gmat,
    unsigned short* __restrict__ Opart, float* __restrict__ lpart)
{
  __shared__ unsigned short ldsK[2][64 * LDK];
  __shared__ unsigned short ldsV[2][64 * LDK];
  __shared__ unsigned short ldsP[4][16 * LDK];   // per-wave P / O-staging
  const int qt = blockIdx.x, b = blockIdx.y, seg = blockIdx.z;
  const int t = threadIdx.x;
  const int wave = t >> 6, lane = t & 63;
  const int l15 = lane & 15, quad = lane >> 4;
  const int q0 = qt * 256 + wave * 64;

  s16x8 aq[4][2];
  const unsigned short* th = thetaT + ((size_t)b * NSP + q0) * ICH;
#pragma unroll
  for (int qs = 0; qs < 4; ++qs)
#pragma unroll
    for (int ks = 0; ks < 2; ++ks)
      aq[qs][ks] = __builtin_bit_cast(s16x8,
          *(const u32x4*)(th + (qs * 16 + l15) * ICH + ks * 32 + quad * 8));

  f32x4 Oacc[4][4];
  f32x4 lacc[4];
#pragma unroll
  for (int i = 0; i < 4; ++i) {
    lacc[i] = (f32x4){0.f, 0.f, 0.f, 0.f};
#pragma unroll
    for (int j = 0; j < 4; ++j) Oacc[i][j] = (f32x4){0.f, 0.f, 0.f, 0.f};
  }

  // ones-column B-frag: B[k][n]=(n==0) -> C col 0 = row-sum of A
  s16x8 bones;
  {
    short v = (l15 == 0) ? (short)0x3F80 : (short)0;
#pragma unroll
    for (int j = 0; j < 8; ++j) bones[j] = v;
  }

  const unsigned short* ph = phiT + (size_t)b * NSP * ICH;
  const unsigned short* gb = gmat + (size_t)b * ICH * NSP;
  const int k0 = seg * SEGK;

  // staging mapping: chunk idx = t + 256*i; idx<512 -> K[key][d], else V^T[d][key]
  auto load_tile = [&](int key0, u32x4* pf) {
#pragma unroll
    for (int i = 0; i < 4; ++i) {
      int idx = t + 256 * i;
      int r2 = (idx >> 3) & 63, c8 = (idx & 7) * 8;
      pf[i] = (idx < 512)
          ? *(const u32x4*)(ph + (size_t)(key0 + r2) * ICH + c8)
          : *(const u32x4*)(gb + (size_t)r2 * NSP + key0 + c8);
    }
  };
  auto store_tile = [&](int buf, const u32x4* pf) {
#pragma unroll
    for (int i = 0; i < 4; ++i) {
      int idx = t + 256 * i;
      int r2 = (idx >> 3) & 63, c8 = (idx & 7) * 8;
      if (idx < 512) *(u32x4*)(&ldsK[buf][r2 * LDK + c8]) = pf[i];
      else           *(u32x4*)(&ldsV[buf][r2 * LDK + c8]) = pf[i];
    }
  };

  u32x4 pf[4];
  load_tile(k0, pf);
  store_tile(0, pf);
  __syncthreads();

  for (int kt = 0; kt < SEGK / 64; ++kt) {
    const int cur = kt & 1;
    const bool more = (kt + 1) < SEGK / 64;
    if (more) load_tile(k0 + (kt + 1) * 64, pf);   // latency overlaps compute

    s16x8 bk[4][2];
#pragma unroll
    for (int kc = 0; kc < 4; ++kc)
#pragma unroll
      for (int ks = 0; ks < 2; ++ks)
        bk[kc][ks] = *(const s16x8*)(&ldsK[cur][(kc * 16 + l15) * LDK + ks * 32 + quad * 8]);
    s16x8 bv[2][4];
#pragma unroll
    for (int ks = 0; ks < 2; ++ks)
#pragma unroll
      for (int ds = 0; ds < 4; ++ds)
        bv[ks][ds] = *(const s16x8*)(&ldsV[cur][(ds * 16 + l15) * LDK + ks * 32 + quad * 8]);

    unsigned short* myP = &ldsP[wave][0];
#pragma unroll
    for (int qs = 0; qs < 4; ++qs) {
#pragma unroll
      for (int kc = 0; kc < 4; ++kc) {
        f32x4 sacc = (f32x4){0.f, 0.f, 0.f, 0.f};
        sacc = __builtin_amdgcn_mfma_f32_16x16x32_bf16(aq[qs][0], bk[kc][0], sacc, 0, 0, 0);
        sacc = __builtin_amdgcn_mfma_f32_16x16x32_bf16(aq[qs][1], bk[kc][1], sacc, 0, 0, 0);
#pragma unroll
        for (int r = 0; r < 4; ++r) {
          float e = exp2f(sacc[r]);        // theta carries log2(e)
          myP[(quad * 4 + r) * LDK + kc * 16 + l15] =
              (unsigned short)(__builtin_bit_cast(unsigned int, e) >> 16);  // trunc bf16
        }
      }
      // consume P immediately (wave-private LDS, in-order)
#pragma unroll
      for (int ks = 0; ks < 2; ++ks) {
        s16x8 ap = *(const s16x8*)(&myP[l15 * LDK + ks * 32 + quad * 8]);
        lacc[qs] = __builtin_amdgcn_mfma_f32_16x16x32_bf16(ap, bones, lacc[qs], 0, 0, 0);
#pragma unroll
        for (int ds = 0; ds < 4; ++ds)
          Oacc[qs][ds] = __builtin_amdgcn_mfma_f32_16x16x32_bf16(ap, bv[ks][ds], Oacc[qs][ds], 0, 0, 0);
      }
    }

    if (more) {
      store_tile(cur ^ 1, pf);   // other buffer: kt-1 readers passed last barrier
      __syncthreads();           // ONE barrier per kt
    }
  }

  // epilogue: O -> wave-private LDS (C-layout) -> 1-KB-dense bf16 stores
  unsigned short* Ob = Opart + (((size_t)seg * NB + b) * NSP + q0) * ICH;
  unsigned short* myP = &ldsP[wave][0];
  const int erow = lane >> 3;
  const int ecol = (lane & 7) * 8;
#pragma unroll
  for (int qs = 0; qs < 4; ++qs) {
#pragma unroll
    for (int ds = 0; ds < 4; ++ds)
#pragma unroll
      for (int r = 0; r < 4; ++r)
        myP[(quad * 4 + r) * LDK + ds * 16 + l15] = f2bf(Oacc[qs][ds][r]);
    u32x4 w0 = *(const u32x4*)(&myP[erow * LDK + ecol]);
    u32x4 w1 = *(const u32x4*)(&myP[(8 + erow) * LDK + ecol]);
    *(u32x4*)(Ob + (qs * 16 + erow) * ICH + ecol) = w0;
    *(u32x4*)(Ob + (qs * 16 + 8 + erow) * ICH + ecol) = w1;
  }
  // l: stage to LDS, one 256-B dense store per wave
  {
    float* myPf = (float*)myP;
    if (l15 == 0) {
#pragma unroll
      for (int qs = 0; qs < 4; ++qs)
#pragma unroll
        for (int r = 0; r < 4; ++r)
          myPf[qs * 16 + quad * 4 + r] = lacc[qs][r];
    }
    float* lb = lpart + ((size_t)seg * NB + b) * NSP + q0;
    lb[lane] = myPf[lane];
  }
}

// ---------------- Kernel 3a: combine partials + W-proj + stats ---------------
__global__ __launch_bounds__(128) void k_wy(
    const unsigned short* __restrict__ Opart, const float* __restrict__ lpart,
    const unsigned short* __restrict__ Wwb,
    float* __restrict__ WyT, float* __restrict__ stat)
{
  const int b = blockIdx.y, nt = blockIdx.x;   // nt 0..127
  const int t = threadIdx.x;
  const int wave = t >> 6, lane = t & 63;
  const int l15 = lane & 15, quad = lane >> 4;
  const int n0 = nt * 32 + wave * 16;
  float ls = 0.f;
#pragma unroll
  for (int s = 0; s < KSPLIT; ++s)
    ls += lpart[((size_t)s * NB + b) * NSP + n0 + l15];
  float inv = 1.0f / ls;
  s16x8 ay[2];
#pragma unroll
  for (int ks = 0; ks < 2; ++ks) {
    float acc8[8];
#pragma unroll
    for (int j = 0; j < 8; ++j) acc8[j] = 0.f;
#pragma unroll
    for (int s = 0; s < KSPLIT; ++s) {
      const unsigned short* op =
          Opart + (((size_t)s * NB + b) * NSP + n0 + l15) * ICH + ks * 32 + quad * 8;
      u32x4 raw = *(const u32x4*)op;
#pragma unroll
      for (int w2 = 0; w2 < 4; ++w2) {
        unsigned int u = raw[w2];
        acc8[2 * w2]     += __builtin_bit_cast(float, u << 16);
        acc8[2 * w2 + 1] += __builtin_bit_cast(float, u & 0xFFFF0000u);
      }
    }
#pragma unroll
    for (int j = 0; j < 8; ++j) ay[ks][j] = (short)f2bf(acc8[j] * inv);
  }
  const unsigned short* Wb = Wwb + 3 * (ICH * CH);   // W region
  s16x8 bw[8][2];
#pragma unroll
  for (int cc = 0; cc < 8; ++cc)
#pragma unroll
    for (int ks = 0; ks < 2; ++ks)
      bw[cc][ks] = __builtin_bit_cast(s16x8,
          *(const u32x4*)(Wb + (cc * 16 + l15) * ICH + ks * 32 + quad * 8));
  float sums[8], sq[8];
#pragma unroll
  for (int cc = 0; cc < 8; ++cc) { sums[cc] = 0.f; sq[cc] = 0.f; }
#pragma unroll
  for (int cc = 0; cc < 8; ++cc) {
    f32x4 acc = (f32x4){0.f, 0.f, 0.f, 0.f};
    acc = __builtin_amdgcn_mfma_f32_16x16x32_bf16(ay[0], bw[cc][0], acc, 0, 0, 0);
    acc = __builtin_amdgcn_mfma_f32_16x16x32_bf16(ay[1], bw[cc][1], acc, 0, 0, 0);
    float* wout = WyT + ((size_t)b * NSP + n0 + quad * 4) * CH + cc * 16 + l15;
#pragma unroll
    for (int r = 0; r < 4; ++r) {
      float v = acc[r];
      sums[cc] += v;
      sq[cc] += v * v;
      wout[r * CH] = v;
    }
  }
#pragma unroll
  for (int cc = 0; cc < 8; ++cc) {
    sums[cc] += __shfl_xor(sums[cc], 16, 64);
    sums[cc] += __shfl_xor(sums[cc], 32, 64);
    sq[cc] += __shfl_xor(sq[cc], 16, 64);
    sq[cc] += __shfl_xor(sq[cc], 32, 64);
  }
  if (quad == 0) {
#pragma unroll
    for (int cc = 0; cc < 8; ++cc) {
      atomicAdd(&stat[(b * CH + cc * 16 + l15) * 2 + 0], sums[cc]);
      atomicAdd(&stat[(b * CH + cc * 16 + l15) * 2 + 1], sq[cc]);
    }
  }
}

// ---------------- Kernel 3b: InstanceNorm + residual, out [B][C][N] ---------
__global__ __launch_bounds__(256) void k_norm(
    const float* __restrict__ WyT, const float* __restrict__ stat,
    const float* __restrict__ x, float* __restrict__ out)
{
  __shared__ float sWy[32 * 132];
  const int nt = blockIdx.x;        // 0..127
  const int b = blockIdx.y;
  const int t = threadIdx.x;
  const int n0 = nt * 32;
#pragma unroll
  for (int i = 0; i < 4; ++i) {
    int idx = t + 256 * i;
    int row = idx >> 5, c4 = idx & 31;
    *(float4*)(&sWy[row * 132 + c4 * 4]) =
        *(const float4*)(WyT + ((size_t)b * NSP + n0 + row) * CH + c4 * 4);
  }
  __syncthreads();
#pragma unroll
  for (int j = 0; j < 4; ++j) {
    int u = t + 256 * j;
    int co = u >> 3, nq = u & 7;
    float s = stat[(b * CH + co) * 2 + 0];
    float ss = stat[(b * CH + co) * 2 + 1];
    float mean = s * (1.f / NSP);
    float var = ss * (1.f / NSP) - mean * mean;
    float rs = rsqrtf(var + 1e-5f);
    float4 xv = *(const float4*)(x + (size_t)(b * CH + co) * NSP + n0 + nq * 4);
    float4 ov;
    ov.x = xv.x + (sWy[(nq * 4 + 0) * 132 + co] - mean) * rs;
    ov.y = xv.y + (sWy[(nq * 4 + 1) * 132 + co] - mean) * rs;
    ov.z = xv.z + (sWy[(nq * 4 + 2) * 132 + co] - mean) * rs;
    ov.w = xv.w + (sWy[(nq * 4 + 3) * 132 + co] - mean) * rs;
    *(float4*)(out + (size_t)(b * CH + co) * NSP + n0 + nq * 4) = ov;
  }
}

extern "C" void kernel_launch(void* const* d_in, const int* in_sizes, int n_in,
                              void* d_out, int out_size, void* d_ws, size_t ws_size,
                              hipStream_t stream)
{
  const float* x  = (const float*)d_in[0];
  const float* gw = (const float*)d_in[1];
  const float* gb = (const float*)d_in[2];
  const float* tw = (const float*)d_in[3];
  const float* tb = (const float*)d_in[4];
  const float* pw = (const float*)d_in[5];
  const float* pb = (const float*)d_in[6];
  const float* Ww = (const float*)d_in[7];
  // d_in[8] = W_b: canceled by InstanceNorm -> unused
  float* out = (float*)d_out;
  char* ws = (char*)d_ws;
  // workspace layout (~33 MB)
  unsigned short* thetaT = (unsigned short*)(ws);                        // 2 MB
  unsigned short* phiT   = (unsigned short*)(ws + (2ull << 20));         // 2 MB
  unsigned short* gmat   = (unsigned short*)(ws + (4ull << 20));         // 2 MB
  float* WyT   = (float*)(ws + (8ull << 20));                            // 8 MB
  float* stat  = (float*)(ws + (16ull << 20));                           // 4 KB
  unsigned short* Wwb = (unsigned short*)(ws + (16ull << 20) + 65536);   // 64 KB
  float* lpart = (float*)(ws + (16ull << 20) + (1ull << 19));            // 512 KB
  unsigned short* Opart = (unsigned short*)(ws + (17ull << 20));         // 16 MB

  k_wconv<<<dim3(32), 256, 0, stream>>>(tw, pw, gw, Ww, Wwb, stat);
  k_proj<<<dim3(128, 4), 128, 0, stream>>>(x, gb, tb, pb, Wwb, thetaT, phiT, gmat);
  k_attn<<<dim3(16, 4, KSPLIT), 256, 0, stream>>>(thetaT, phiT, gmat, Opart, lpart);
  k_wy<<<dim3(128, 4), 128, 0, stream>>>(Opart, lpart, Wwb, WyT, stat);
  k_norm<<<dim3(128, 4), 256, 0, stream>>>(WyT, stat, x, out);
}